// Round 6
// baseline (8579.427 us; speedup 1.0000x reference)
//
#include <hip/hip_runtime.h>
#include <math.h>

typedef unsigned short u16;
typedef __attribute__((ext_vector_type(8))) short short8;
typedef __attribute__((ext_vector_type(4))) float f32x4;

#define LAYERS 8
#define D 1024
#define NH 16
#define DKH 64
#define DFF 4096
#define SEQ 66
#define TT 67
#define BATCH 256
#define ROWS (BATCH*TT)   /* 17152 = 67*256 */
#define VOCAB 4096
#define TP 80
#define KP 96
#define QS 3072           /* merged qkv row stride */

__device__ __forceinline__ float bf2f(u16 v){
  unsigned int u = ((unsigned int)v) << 16;
  return __builtin_bit_cast(float, u);
}
__device__ __forceinline__ u16 f2bf(float f){
  unsigned int u = __builtin_bit_cast(unsigned int, f);
  u += 0x7FFFu + ((u >> 16) & 1u);
  return (u16)(u >> 16);
}
__device__ __forceinline__ void gload16(const u16* g, u16* l){
  __builtin_amdgcn_global_load_lds((const __attribute__((address_space(1))) void*)g,
                                   (__attribute__((address_space(3))) void*)l, 16, 0, 0);
}

// ---------------- transpose + cast f32 -> bf16 ----------------
__global__ void transpose_cast(const float* __restrict__ src, u16* __restrict__ dst,
                               int R, int C){
  __shared__ float tile[32][33];
  const int c0 = blockIdx.x * 32, r0 = blockIdx.y * 32;
  const int tx = threadIdx.x, ty = threadIdx.y;
  #pragma unroll
  for (int i = 0; i < 32; i += 8)
    tile[ty + i][tx] = src[(size_t)(r0 + ty + i) * C + (c0 + tx)];
  __syncthreads();
  #pragma unroll
  for (int i = 0; i < 32; i += 8)
    dst[(size_t)(c0 + ty + i) * R + (r0 + tx)] = f2bf(tile[tx][ty + i]);
}

// ---------------- embedding + positional encoding ----------------
__global__ void embed_kernel(const int* __restrict__ x, const float* __restrict__ emb,
                             const float* __restrict__ pool, float* __restrict__ h,
                             u16* __restrict__ hb){
  const int row = blockIdx.x;
  const int b = row / TT, t = row % TT;
  const int d0 = threadIdx.x * 4;
  float v[4];
  if (t == 0){
    const float4 p4 = *(const float4*)&pool[d0];
    v[0] = p4.x; v[1] = p4.y; v[2] = p4.z; v[3] = p4.w;
  } else {
    const int id = x[b * SEQ + (t - 1)];
    const float4 e4 = *(const float4*)&emb[(size_t)id * D + d0];
    v[0] = e4.x * 32.f; v[1] = e4.y * 32.f; v[2] = e4.z * 32.f; v[3] = e4.w * 32.f;
  }
  const float c = -logf(10000.f) / (float)D;
  float o[4];
  #pragma unroll
  for (int j = 0; j < 4; j++){
    const int d = d0 + j;
    const int p = d >> 1;
    const float freq = expf((float)(2 * p) * c);
    const float ang = (float)t * freq;
    const float pe = (d & 1) ? cosf(ang) : sinf(ang);
    o[j] = v[j] + pe;
  }
  *(float4*)&h[(size_t)row * D + d0] = make_float4(o[0], o[1], o[2], o[3]);
  const unsigned int lo = (unsigned)f2bf(o[0]) | ((unsigned)f2bf(o[1]) << 16);
  const unsigned int hi = (unsigned)f2bf(o[2]) | ((unsigned)f2bf(o[3]) << 16);
  *(uint2*)&hb[(size_t)row * D + d0] = make_uint2(lo, hi);
}

// ---------------- fused residual + LayerNorm ----------------
__global__ void ln_kernel(float* __restrict__ h, const float* __restrict__ res,
                          u16* __restrict__ hb, const float* __restrict__ g,
                          const float* __restrict__ bta){
  const int row = blockIdx.x;
  const int tid = threadIdx.x;
  const size_t off = (size_t)row * D + tid * 4;
  const float4 a = *(const float4*)&h[off];
  const float4 r4 = *(const float4*)&res[off];
  const float s0 = a.x + r4.x, s1 = a.y + r4.y, s2 = a.z + r4.z, s3 = a.w + r4.w;
  float sum = s0 + s1 + s2 + s3;
  float sq = s0*s0 + s1*s1 + s2*s2 + s3*s3;
  #pragma unroll
  for (int m = 32; m >= 1; m >>= 1){ sum += __shfl_xor(sum, m); sq += __shfl_xor(sq, m); }
  __shared__ float red[2][4];
  const int w = tid >> 6;
  if ((tid & 63) == 0){ red[0][w] = sum; red[1][w] = sq; }
  __syncthreads();
  sum = red[0][0] + red[0][1] + red[0][2] + red[0][3];
  sq  = red[1][0] + red[1][1] + red[1][2] + red[1][3];
  const float mean = sum * (1.f / D);
  const float var = sq * (1.f / D) - mean * mean;
  const float rs = rsqrtf(var + 1e-5f);
  const float4 gv = *(const float4*)&g[tid * 4];
  const float4 bv = *(const float4*)&bta[tid * 4];
  const float o0 = (s0 - mean) * rs * gv.x + bv.x;
  const float o1 = (s1 - mean) * rs * gv.y + bv.y;
  const float o2 = (s2 - mean) * rs * gv.z + bv.z;
  const float o3 = (s3 - mean) * rs * gv.w + bv.w;
  *(float4*)&h[off] = make_float4(o0, o1, o2, o3);
  const unsigned int lo = (unsigned)f2bf(o0) | ((unsigned)f2bf(o1) << 16);
  const unsigned int hi = (unsigned)f2bf(o2) | ((unsigned)f2bf(o3) << 16);
  *(uint2*)&hb[off] = make_uint2(lo, hi);
}

// ---------------- MFMA attention: one block (4 waves) per (batch, head) ----------------
__global__ __launch_bounds__(256) void attn_kernel(const u16* __restrict__ qkv,
    const float* __restrict__ rel, u16* __restrict__ ctxb){
  __shared__ u16 Qf[8 * 81 * 8];
  __shared__ u16 Kf[8 * 81 * 8];
  __shared__ u16 Vf[12 * 65 * 8];
  __shared__ u16 Pf[12 * 81 * 8];
  __shared__ float Ss[TP][84];
  const int bh = blockIdx.x;
  const int b = bh >> 4, hh = bh & 15;
  const int tid = threadIdx.x, w = tid >> 6, l = tid & 63;
  const size_t qvbase = (size_t)(b * TT) * QS + hh * DKH;
  const size_t obase  = (size_t)(b * TT) * D + hh * DKH;

  {
    const int r0 = tid >> 4, c4 = (tid & 15) * 4;
    const int g = c4 >> 3, e = c4 & 7;
    for (int r = r0; r < TP; r += 16){
      uint2 q2 = make_uint2(0u, 0u), k2 = make_uint2(0u, 0u);
      if (r < TT){
        q2 = *(const uint2*)&qkv[qvbase + (size_t)r * QS + c4];
        k2 = *(const uint2*)&qkv[qvbase + 1024 + (size_t)r * QS + c4];
      }
      *(uint2*)&Qf[(g * 81 + r) * 8 + e] = q2;
      *(uint2*)&Kf[(g * 81 + r) * 8 + e] = k2;
    }
    for (int j = r0; j < KP; j += 16){
      u16 v4[4] = {0, 0, 0, 0};
      if (j < TT) *(uint2*)v4 = *(const uint2*)&qkv[qvbase + 2048 + (size_t)j * QS + c4];
      const int gg = j >> 3, ee = j & 7;
      #pragma unroll
      for (int d = 0; d < 4; d++)
        Vf[(gg * 65 + (c4 + d)) * 8 + ee] = v4[d];
    }
  }
  __syncthreads();

  const int fr = l & 15, gg = l >> 4;
  for (int p = w; p < 25; p += 4){
    const int rt = p / 5, ct = p % 5;
    f32x4 acc = {};
    #pragma unroll
    for (int kk = 0; kk < 2; kk++){
      const short8 a  = *(const short8*)&Qf[((kk * 4 + gg) * 81 + rt * 16 + fr) * 8];
      const short8 bf = *(const short8*)&Kf[((kk * 4 + gg) * 81 + ct * 16 + fr) * 8];
      acc = __builtin_amdgcn_mfma_f32_16x16x32_bf16(a, bf, acc, 0, 0, 0);
    }
    const int col = ct * 16 + fr;
    #pragma unroll
    for (int r = 0; r < 4; r++){
      const int row = rt * 16 + gg * 4 + r;
      float sv = -1e30f;
      if (row < TT && col < TT)
        sv = acc[r] * 0.125f + rel[((size_t)hh * 78 + row) * 78 + col];
      Ss[row][col] = sv;
    }
  }
  __syncthreads();

  for (int row = w; row < TP; row += 4){
    const float s1 = Ss[row][l];
    const float s2 = (l < 16) ? Ss[row][64 + l] : -1e30f;
    float mx = fmaxf(s1, s2);
    #pragma unroll
    for (int m = 32; m >= 1; m >>= 1) mx = fmaxf(mx, __shfl_xor(mx, m));
    const float e1 = __expf(s1 - mx);
    const float e2 = (l < 16) ? __expf(s2 - mx) : 0.f;
    float sum = e1 + e2;
    #pragma unroll
    for (int m = 32; m >= 1; m >>= 1) sum += __shfl_xor(sum, m);
    const float inv = 1.f / sum;
    Pf[((l >> 3) * 81 + row) * 8 + (l & 7)] = f2bf(e1 * inv);
    if (l < 16){
      Pf[((8  + (l >> 3)) * 81 + row) * 8 + (l & 7)] = f2bf(e2 * inv);
      Pf[((10 + (l >> 3)) * 81 + row) * 8 + (l & 7)] = 0;
    }
  }
  __syncthreads();

  for (int p = w; p < 20; p += 4){
    const int rt = p >> 2, ct = p & 3;
    f32x4 acc = {};
    #pragma unroll
    for (int kk = 0; kk < 3; kk++){
      const short8 a  = *(const short8*)&Pf[((kk * 4 + gg) * 81 + rt * 16 + fr) * 8];
      const short8 bf = *(const short8*)&Vf[((kk * 4 + gg) * 65 + ct * 16 + fr) * 8];
      acc = __builtin_amdgcn_mfma_f32_16x16x32_bf16(a, bf, acc, 0, 0, 0);
    }
    #pragma unroll
    for (int r = 0; r < 4; r++){
      const int row = rt * 16 + gg * 4 + r;
      if (row < TT)
        ctxb[obase + (size_t)row * D + ct * 16 + fr] = f2bf(acc[r]);
    }
  }
}

// ---------------- 256x256 bf16 MFMA GEMM, triple-buffered depth-2 pipeline ----------------
// 8 waves (2Mx4N), BK=32, 3 LDS buffers (96KB), prefetch 2 K-steps ahead,
// counted vmcnt (8/4/0 tail), raw s_barrier (loads stay in flight across barriers).
// C = A @ Bt^T (+bias)(+gelu); A: M x K bf16 (lda), Bt: N x K bf16, C: M x N
template<int OBF16, int BIAS, int GELU>
__global__ __launch_bounds__(512, 1) void gemm256(
    const u16* __restrict__ A, int lda,
    const u16* __restrict__ Bt,
    void* __restrict__ Cv, int ldc,
    const float* __restrict__ bias, int K)
{
  __shared__ u16 S[49152];   // 3 x (A[8192] + B[8192]) u16
  const int tid = threadIdx.x;
  const int l = tid & 63, w = tid >> 6;
  const int wr = w >> 2, wc = w & 3;          // 2 x 4 wave grid
  const int m0 = blockIdx.x * 256, n0 = blockIdx.y * 256;
  // staging: lane l of wave w covers row w*16+(l>>2) (and +128), 16B unit l&3
  const int srow = w * 16 + (l >> 2);
  const int su   = (l & 3) * 8;
  const u16* gA0 = A  + (size_t)(m0 + srow)       * lda + su;
  const u16* gA1 = A  + (size_t)(m0 + 128 + srow) * lda + su;
  const u16* gB0 = Bt + (size_t)(n0 + srow)       * K   + su;
  const u16* gB1 = Bt + (size_t)(n0 + 128 + srow) * K   + su;
  const int fr = l & 15, q = l >> 4;
  const int aoff = (wr * 128 + fr) * 32 + q * 8;
  const int boff = (wc * 64 + fr) * 32 + q * 8;
  f32x4 acc[8][4] = {};
  const int nkt = K >> 5;
#define STAGE256(sel, kt_) do { \
    u16* dst_ = &S[(sel) * 16384 + w * 512]; \
    const int kc_ = (kt_) * 32; \
    gload16(gA0 + kc_, dst_); \
    gload16(gA1 + kc_, dst_ + 4096); \
    gload16(gB0 + kc_, dst_ + 8192); \
    gload16(gB1 + kc_, dst_ + 8192 + 4096); \
  } while (0)
  STAGE256(0, 0);
  STAGE256(1, 1);
  int cur = 0;
  #pragma unroll 1
  for (int kt = 0; kt < nkt; ++kt){
    if (kt + 2 < nkt){
      STAGE256((kt + 2) % 3, kt + 2);
      asm volatile("s_waitcnt vmcnt(8)" ::: "memory");   // tile kt landed; kt+1, kt+2 in flight
    } else if (kt + 1 < nkt){
      asm volatile("s_waitcnt vmcnt(4)" ::: "memory");
    } else {
      asm volatile("s_waitcnt vmcnt(0)" ::: "memory");
    }
    __builtin_amdgcn_sched_barrier(0);
    __builtin_amdgcn_s_barrier();
    __builtin_amdgcn_sched_barrier(0);
    const u16* Ab = &S[cur * 16384];
    const u16* Bb = Ab + 8192;
    short8 b0 = *(const short8*)&Bb[boff];
    short8 b1 = *(const short8*)&Bb[boff + 512];
    short8 b2 = *(const short8*)&Bb[boff + 1024];
    short8 b3 = *(const short8*)&Bb[boff + 1536];
    #pragma unroll
    for (int m = 0; m < 8; m++){
      const short8 am = *(const short8*)&Ab[aoff + m * 512];
      acc[m][0] = __builtin_amdgcn_mfma_f32_16x16x32_bf16(am, b0, acc[m][0], 0, 0, 0);
      acc[m][1] = __builtin_amdgcn_mfma_f32_16x16x32_bf16(am, b1, acc[m][1], 0, 0, 0);
      acc[m][2] = __builtin_amdgcn_mfma_f32_16x16x32_bf16(am, b2, acc[m][2], 0, 0, 0);
      acc[m][3] = __builtin_amdgcn_mfma_f32_16x16x32_bf16(am, b3, acc[m][3], 0, 0, 0);
    }
    __builtin_amdgcn_sched_barrier(0);
    __builtin_amdgcn_s_barrier();
    cur = (cur == 2) ? 0 : cur + 1;
  }
#undef STAGE256
  const int rg = q * 4;
  #pragma unroll
  for (int m = 0; m < 8; m++){
    #pragma unroll
    for (int n = 0; n < 4; n++){
      const int col = n0 + wc * 64 + n * 16 + fr;
      const float bv = BIAS ? bias[col] : 0.f;
      #pragma unroll
      for (int r = 0; r < 4; r++){
        const int row = m0 + wr * 128 + m * 16 + rg + r;
        float xv = acc[m][n][r] + bv;
        if (GELU) xv = 0.5f * xv * (1.f + erff(xv * 0.70710678118f));
        if (OBF16) ((u16*)Cv)[(size_t)row * ldc + col] = f2bf(xv);
        else       ((float*)Cv)[(size_t)row * ldc + col] = xv;
      }
    }
  }
}

// ---------------- 128x128 GEMM (final head matmul) ----------------
template<int OBF16, int BIAS, int GELU>
__global__ __launch_bounds__(256, 2) void gemm_bt(
    const u16* __restrict__ A, int lda,
    const u16* __restrict__ Bt,
    void* __restrict__ Cv, int ldc,
    const float* __restrict__ bias, int K)
{
  __shared__ u16 As[128 * 32];
  __shared__ u16 Bs[128 * 32];
  const int m0 = blockIdx.x * 128, n0 = blockIdx.y * 128;
  const int tid = threadIdx.x;
  const int l = tid & 63, w = tid >> 6;
  const int wr = w >> 1, wc = w & 1;
  f32x4 acc[4][4] = {};
  const int lr = l >> 2;
  const int lseg = (l & 3) * 8;
  u16* aB0 = &As[(w * 32) * 32];
  u16* aB1 = &As[(w * 32 + 16) * 32];
  u16* bB0 = &Bs[(w * 32) * 32];
  u16* bB1 = &Bs[(w * 32 + 16) * 32];
  const u16* ga0 = A + (size_t)(m0 + w * 32 + lr) * lda + lseg;
  const u16* ga1 = A + (size_t)(m0 + w * 32 + 16 + lr) * lda + lseg;
  const u16* gb0 = Bt + (size_t)(n0 + w * 32 + lr) * K + lseg;
  const u16* gb1 = Bt + (size_t)(n0 + w * 32 + 16 + lr) * K + lseg;
  const int fr = l & 15, kg = (l >> 4) * 8;
  for (int kt = 0; kt < K; kt += 32){
    __syncthreads();
    gload16(ga0 + kt, aB0);
    gload16(ga1 + kt, aB1);
    gload16(gb0 + kt, bB0);
    gload16(gb1 + kt, bB1);
    __syncthreads();
    short8 af[4], bf[4];
    #pragma unroll
    for (int i = 0; i < 4; i++){
      af[i] = *(const short8*)&As[(wr * 64 + i * 16 + fr) * 32 + kg];
      bf[i] = *(const short8*)&Bs[(wc * 64 + i * 16 + fr) * 32 + kg];
    }
    #pragma unroll
    for (int i = 0; i < 4; i++)
      #pragma unroll
      for (int j = 0; j < 4; j++)
        acc[i][j] = __builtin_amdgcn_mfma_f32_16x16x32_bf16(af[i], bf[j], acc[i][j], 0, 0, 0);
  }
  const int rg = (l >> 4) * 4;
  #pragma unroll
  for (int i = 0; i < 4; i++){
    #pragma unroll
    for (int j = 0; j < 4; j++){
      const int col = n0 + wc * 64 + j * 16 + fr;
      const float bv = BIAS ? bias[col] : 0.f;
      #pragma unroll
      for (int r = 0; r < 4; r++){
        const int row = m0 + wr * 64 + i * 16 + rg + r;
        float xv = acc[i][j][r] + bv;
        if (GELU) xv = 0.5f * xv * (1.f + erff(xv * 0.70710678118f));
        if (OBF16) ((u16*)Cv)[(size_t)row * ldc + col] = f2bf(xv);
        else       ((float*)Cv)[(size_t)row * ldc + col] = xv;
      }
    }
  }
}

extern "C" void kernel_launch(void* const* d_in, const int* in_sizes, int n_in,
                              void* d_out, int out_size, void* d_ws, size_t ws_size,
                              hipStream_t stream) {
  const int*   x       = (const int*)  d_in[0];
  const float* emb     = (const float*)d_in[1];
  const float* pool    = (const float*)d_in[2];
  const float* Wq      = (const float*)d_in[3];
  const float* Wk      = (const float*)d_in[4];
  const float* Wv      = (const float*)d_in[5];
  const float* Wo      = (const float*)d_in[6];
  const float* rel     = (const float*)d_in[7];
  const float* ln1_g   = (const float*)d_in[8];
  const float* ln1_b   = (const float*)d_in[9];
  const float* ln2_g   = (const float*)d_in[10];
  const float* ln2_b   = (const float*)d_in[11];
  const float* W1      = (const float*)d_in[12];
  const float* b1      = (const float*)d_in[13];
  const float* W2      = (const float*)d_in[14];
  const float* b2      = (const float*)d_in[15];
  const float* Wout    = (const float*)d_in[16];
  const float* bout    = (const float*)d_in[17];
  float* out = (float*)d_out;

  const size_t SZ_WDD  = (size_t)D * D * 2;
  const size_t SZ_WDF  = (size_t)D * DFF * 2;
  const size_t SZ_H    = (size_t)ROWS * D * 4;
  const size_t SZ_HB   = (size_t)ROWS * D * 2;
  const size_t need = 4*SZ_WDD + 3*SZ_WDF + SZ_H + SZ_HB + 4*SZ_HB + SZ_H;
  if (ws_size < need) return;

  char* p = (char*)d_ws;
  u16* WqkvT = (u16*)p; p += 3*SZ_WDD;   // rows [0,1024)=Wq^T, [1024,2048)=Wk^T, [2048,3072)=Wv^T
  u16* WoT   = (u16*)p; p += SZ_WDD;
  u16* W1T   = (u16*)p; p += SZ_WDF;
  u16* W2T   = (u16*)p; p += SZ_WDF;
  u16* WouT  = (u16*)p; p += SZ_WDF;
  float* h   = (float*)p; p += SZ_H;
  u16* hb    = (u16*)p; p += SZ_HB;
  u16* qkv   = (u16*)p; p += 3*SZ_HB;    // [ROWS][3072]
  u16* ctxb  = (u16*)p; p += SZ_HB;
  u16* gb    = qkv;                       // FFN hidden aliases qkv+ctx (4*SZ_HB)
  float* tmp = (float*)p; p += SZ_H;

  dim3 tb(32, 8);
  transpose_cast<<<dim3(VOCAB/32, D/32), tb, 0, stream>>>(Wout, WouT, D, VOCAB);
  embed_kernel<<<ROWS, 256, 0, stream>>>(x, emb, pool, h, hb);

  for (int l = 0; l < LAYERS; ++l){
    const size_t wo = (size_t)l * D * D;
    const size_t wf = (size_t)l * D * DFF;
    transpose_cast<<<dim3(D/32,   D/32),   tb, 0, stream>>>(Wq + wo, WqkvT,            D, D);
    transpose_cast<<<dim3(D/32,   D/32),   tb, 0, stream>>>(Wk + wo, WqkvT + D*D,      D, D);
    transpose_cast<<<dim3(D/32,   D/32),   tb, 0, stream>>>(Wv + wo, WqkvT + 2*D*D,    D, D);
    transpose_cast<<<dim3(D/32,   D/32),   tb, 0, stream>>>(Wo + wo, WoT, D, D);
    transpose_cast<<<dim3(DFF/32, D/32),   tb, 0, stream>>>(W1 + wf, W1T, D, DFF);
    transpose_cast<<<dim3(D/32,   DFF/32), tb, 0, stream>>>(W2 + wf, W2T, DFF, D);

    gemm256<1,0,0><<<dim3(ROWS/256, QS/256),  512, 0, stream>>>(hb, D, WqkvT, qkv, QS, nullptr, D);
    attn_kernel<<<BATCH*NH, 256, 0, stream>>>(qkv, rel + (size_t)l*NH*78*78, ctxb);
    gemm256<0,0,0><<<dim3(ROWS/256, D/256),   512, 0, stream>>>(ctxb, D, WoT, tmp, D, nullptr, D);
    ln_kernel<<<ROWS, 256, 0, stream>>>(h, tmp, hb, ln1_g + l*D, ln1_b + l*D);
    gemm256<1,1,1><<<dim3(ROWS/256, DFF/256), 512, 0, stream>>>(hb, D, W1T, gb, DFF, b1 + l*DFF, D);
    gemm256<0,1,0><<<dim3(ROWS/256, D/256),   512, 0, stream>>>(gb, DFF, W2T, tmp, D, b2 + l*D, DFF);
    ln_kernel<<<ROWS, 256, 0, stream>>>(h, tmp, hb, ln2_g + l*D, ln2_b + l*D);
  }
  gemm_bt<0,1,0><<<dim3(BATCH/128, VOCAB/128), 256, 0, stream>>>(
      hb, TT * D, WouT, out, VOCAB, bout, D);
}

// Round 7
// 8350.712 us; speedup vs baseline: 1.0274x; 1.0274x over previous
//
#include <hip/hip_runtime.h>
#include <math.h>

typedef unsigned short u16;
typedef __attribute__((ext_vector_type(8))) short short8;
typedef __attribute__((ext_vector_type(4))) float f32x4;

#define LAYERS 8
#define D 1024
#define NH 16
#define DKH 64
#define DFF 4096
#define SEQ 66
#define TT 67
#define BATCH 256
#define ROWS (BATCH*TT)   /* 17152 = 67*256 */
#define VOCAB 4096
#define TP 80
#define KP 96
#define QS 3072           /* merged qkv row stride */

__device__ __forceinline__ float bf2f(u16 v){
  unsigned int u = ((unsigned int)v) << 16;
  return __builtin_bit_cast(float, u);
}
__device__ __forceinline__ u16 f2bf(float f){
  unsigned int u = __builtin_bit_cast(unsigned int, f);
  u += 0x7FFFu + ((u >> 16) & 1u);
  return (u16)(u >> 16);
}
__device__ __forceinline__ void gload16(const u16* g, u16* l){
  __builtin_amdgcn_global_load_lds((const __attribute__((address_space(1))) void*)g,
                                   (__attribute__((address_space(3))) void*)l, 16, 0, 0);
}

// ---------------- transpose + cast f32 -> bf16 ----------------
__global__ void transpose_cast(const float* __restrict__ src, u16* __restrict__ dst,
                               int R, int C){
  __shared__ float tile[32][33];
  const int c0 = blockIdx.x * 32, r0 = blockIdx.y * 32;
  const int tx = threadIdx.x, ty = threadIdx.y;
  #pragma unroll
  for (int i = 0; i < 32; i += 8)
    tile[ty + i][tx] = src[(size_t)(r0 + ty + i) * C + (c0 + tx)];
  __syncthreads();
  #pragma unroll
  for (int i = 0; i < 32; i += 8)
    dst[(size_t)(c0 + ty + i) * R + (r0 + tx)] = f2bf(tile[tx][ty + i]);
}

// ---------------- embedding + positional encoding ----------------
__global__ void embed_kernel(const int* __restrict__ x, const float* __restrict__ emb,
                             const float* __restrict__ pool, float* __restrict__ h,
                             u16* __restrict__ hb){
  const int row = blockIdx.x;
  const int b = row / TT, t = row % TT;
  const int d0 = threadIdx.x * 4;
  float v[4];
  if (t == 0){
    const float4 p4 = *(const float4*)&pool[d0];
    v[0] = p4.x; v[1] = p4.y; v[2] = p4.z; v[3] = p4.w;
  } else {
    const int id = x[b * SEQ + (t - 1)];
    const float4 e4 = *(const float4*)&emb[(size_t)id * D + d0];
    v[0] = e4.x * 32.f; v[1] = e4.y * 32.f; v[2] = e4.z * 32.f; v[3] = e4.w * 32.f;
  }
  const float c = -logf(10000.f) / (float)D;
  float o[4];
  #pragma unroll
  for (int j = 0; j < 4; j++){
    const int d = d0 + j;
    const int p = d >> 1;
    const float freq = expf((float)(2 * p) * c);
    const float ang = (float)t * freq;
    const float pe = (d & 1) ? cosf(ang) : sinf(ang);
    o[j] = v[j] + pe;
  }
  *(float4*)&h[(size_t)row * D + d0] = make_float4(o[0], o[1], o[2], o[3]);
  const unsigned int lo = (unsigned)f2bf(o[0]) | ((unsigned)f2bf(o[1]) << 16);
  const unsigned int hi = (unsigned)f2bf(o[2]) | ((unsigned)f2bf(o[3]) << 16);
  *(uint2*)&hb[(size_t)row * D + d0] = make_uint2(lo, hi);
}

// ---------------- fused residual + LayerNorm ----------------
__global__ void ln_kernel(float* __restrict__ h, const float* __restrict__ res,
                          u16* __restrict__ hb, const float* __restrict__ g,
                          const float* __restrict__ bta){
  const int row = blockIdx.x;
  const int tid = threadIdx.x;
  const size_t off = (size_t)row * D + tid * 4;
  const float4 a = *(const float4*)&h[off];
  const float4 r4 = *(const float4*)&res[off];
  const float s0 = a.x + r4.x, s1 = a.y + r4.y, s2 = a.z + r4.z, s3 = a.w + r4.w;
  float sum = s0 + s1 + s2 + s3;
  float sq = s0*s0 + s1*s1 + s2*s2 + s3*s3;
  #pragma unroll
  for (int m = 32; m >= 1; m >>= 1){ sum += __shfl_xor(sum, m); sq += __shfl_xor(sq, m); }
  __shared__ float red[2][4];
  const int w = tid >> 6;
  if ((tid & 63) == 0){ red[0][w] = sum; red[1][w] = sq; }
  __syncthreads();
  sum = red[0][0] + red[0][1] + red[0][2] + red[0][3];
  sq  = red[1][0] + red[1][1] + red[1][2] + red[1][3];
  const float mean = sum * (1.f / D);
  const float var = sq * (1.f / D) - mean * mean;
  const float rs = rsqrtf(var + 1e-5f);
  const float4 gv = *(const float4*)&g[tid * 4];
  const float4 bv = *(const float4*)&bta[tid * 4];
  const float o0 = (s0 - mean) * rs * gv.x + bv.x;
  const float o1 = (s1 - mean) * rs * gv.y + bv.y;
  const float o2 = (s2 - mean) * rs * gv.z + bv.z;
  const float o3 = (s3 - mean) * rs * gv.w + bv.w;
  *(float4*)&h[off] = make_float4(o0, o1, o2, o3);
  const unsigned int lo = (unsigned)f2bf(o0) | ((unsigned)f2bf(o1) << 16);
  const unsigned int hi = (unsigned)f2bf(o2) | ((unsigned)f2bf(o3) << 16);
  *(uint2*)&hb[off] = make_uint2(lo, hi);
}

// ---------------- MFMA attention: one block (4 waves) per (batch, head) ----------------
__global__ __launch_bounds__(256) void attn_kernel(const u16* __restrict__ qkv,
    const float* __restrict__ rel, u16* __restrict__ ctxb){
  __shared__ u16 Qf[8 * 81 * 8];
  __shared__ u16 Kf[8 * 81 * 8];
  __shared__ u16 Vf[12 * 65 * 8];
  __shared__ u16 Pf[12 * 81 * 8];
  __shared__ float Ss[TP][84];
  const int bh = blockIdx.x;
  const int b = bh >> 4, hh = bh & 15;
  const int tid = threadIdx.x, w = tid >> 6, l = tid & 63;
  const size_t qvbase = (size_t)(b * TT) * QS + hh * DKH;
  const size_t obase  = (size_t)(b * TT) * D + hh * DKH;

  {
    const int r0 = tid >> 4, c4 = (tid & 15) * 4;
    const int g = c4 >> 3, e = c4 & 7;
    for (int r = r0; r < TP; r += 16){
      uint2 q2 = make_uint2(0u, 0u), k2 = make_uint2(0u, 0u);
      if (r < TT){
        q2 = *(const uint2*)&qkv[qvbase + (size_t)r * QS + c4];
        k2 = *(const uint2*)&qkv[qvbase + 1024 + (size_t)r * QS + c4];
      }
      *(uint2*)&Qf[(g * 81 + r) * 8 + e] = q2;
      *(uint2*)&Kf[(g * 81 + r) * 8 + e] = k2;
    }
    for (int j = r0; j < KP; j += 16){
      u16 v4[4] = {0, 0, 0, 0};
      if (j < TT) *(uint2*)v4 = *(const uint2*)&qkv[qvbase + 2048 + (size_t)j * QS + c4];
      const int gg = j >> 3, ee = j & 7;
      #pragma unroll
      for (int d = 0; d < 4; d++)
        Vf[(gg * 65 + (c4 + d)) * 8 + ee] = v4[d];
    }
  }
  __syncthreads();

  const int fr = l & 15, gg = l >> 4;
  for (int p = w; p < 25; p += 4){
    const int rt = p / 5, ct = p % 5;
    f32x4 acc = {};
    #pragma unroll
    for (int kk = 0; kk < 2; kk++){
      const short8 a  = *(const short8*)&Qf[((kk * 4 + gg) * 81 + rt * 16 + fr) * 8];
      const short8 bf = *(const short8*)&Kf[((kk * 4 + gg) * 81 + ct * 16 + fr) * 8];
      acc = __builtin_amdgcn_mfma_f32_16x16x32_bf16(a, bf, acc, 0, 0, 0);
    }
    const int col = ct * 16 + fr;
    #pragma unroll
    for (int r = 0; r < 4; r++){
      const int row = rt * 16 + gg * 4 + r;
      float sv = -1e30f;
      if (row < TT && col < TT)
        sv = acc[r] * 0.125f + rel[((size_t)hh * 78 + row) * 78 + col];
      Ss[row][col] = sv;
    }
  }
  __syncthreads();

  for (int row = w; row < TP; row += 4){
    const float s1 = Ss[row][l];
    const float s2 = (l < 16) ? Ss[row][64 + l] : -1e30f;
    float mx = fmaxf(s1, s2);
    #pragma unroll
    for (int m = 32; m >= 1; m >>= 1) mx = fmaxf(mx, __shfl_xor(mx, m));
    const float e1 = __expf(s1 - mx);
    const float e2 = (l < 16) ? __expf(s2 - mx) : 0.f;
    float sum = e1 + e2;
    #pragma unroll
    for (int m = 32; m >= 1; m >>= 1) sum += __shfl_xor(sum, m);
    const float inv = 1.f / sum;
    Pf[((l >> 3) * 81 + row) * 8 + (l & 7)] = f2bf(e1 * inv);
    if (l < 16){
      Pf[((8  + (l >> 3)) * 81 + row) * 8 + (l & 7)] = f2bf(e2 * inv);
      Pf[((10 + (l >> 3)) * 81 + row) * 8 + (l & 7)] = 0;
    }
  }
  __syncthreads();

  for (int p = w; p < 20; p += 4){
    const int rt = p >> 2, ct = p & 3;
    f32x4 acc = {};
    #pragma unroll
    for (int kk = 0; kk < 3; kk++){
      const short8 a  = *(const short8*)&Pf[((kk * 4 + gg) * 81 + rt * 16 + fr) * 8];
      const short8 bf = *(const short8*)&Vf[((kk * 4 + gg) * 65 + ct * 16 + fr) * 8];
      acc = __builtin_amdgcn_mfma_f32_16x16x32_bf16(a, bf, acc, 0, 0, 0);
    }
    #pragma unroll
    for (int r = 0; r < 4; r++){
      const int row = rt * 16 + gg * 4 + r;
      if (row < TT)
        ctxb[obase + (size_t)row * D + ct * 16 + fr] = f2bf(acc[r]);
    }
  }
}

// ---------------- 256x256 bf16 MFMA GEMM — 8-phase schedule (m201-style) ----------------
// 8 waves (2Mx4N), BK=64, dbuf slots, 128KB LDS; per phase: vmcnt(4)+s_barrier,
// 12 ds_read_b128 + 1 half-tile stage (2 gload_lds) + 16 MFMA (one quadrant).
// LDS [256][64] linear, T2 swizzle via pre-swizzled global source + swizzled read
// (involution: 16B-unit ^= row&7).  C = A @ Bt^T (+bias)(+gelu).
template<int OBF16, int BIAS, int GELU>
__global__ __launch_bounds__(512, 1) void gemm8p(
    const u16* __restrict__ A, int lda,
    const u16* __restrict__ Bt,
    void* __restrict__ Cv, int ldc,
    const float* __restrict__ bias, int K)
{
  __shared__ u16 S[65536];   // A: [2][256][64] at 0; B: [2][256][64] at 32768
  const int tid = threadIdx.x, l = tid & 63, w = tid >> 6;
  const int wr = w >> 2, wc = w & 3;
  const int m0 = blockIdx.x * 256, n0 = blockIdx.y * 256;
  const int fr = l & 15, q = l >> 4;
  const int srw = tid >> 3, sseg = tid & 7;   // stage: row-in-64 (0..63), 16B-seg (0..7)
  const int wub = srw & 56;                   // wave-uniform row base (w*8)
  f32x4 acc[8][4] = {};

  auto stageA = [&](int slot, int mp, int kb){
    #pragma unroll
    for (int j = 0; j < 2; j++){
      const int rb = j * 128 + mp * 64;
      const int grow = rb + srw;
      const u16* src = A + (size_t)(m0 + grow) * lda + kb + ((sseg ^ (grow & 7)) << 3);
      u16* dst = &S[slot * 16384 + (rb + wub) * 64];
      gload16(src, dst);
    }
  };
  auto stageB = [&](int slot, int np, int kb){
    #pragma unroll
    for (int j = 0; j < 2; j++){
      const int rp = j * 64 + srw;
      const int grow = ((rp >> 5) << 6) + np * 32 + (rp & 31);
      const int rp0 = j * 64 + wub;
      const int row0 = ((rp0 >> 5) << 6) + np * 32 + (rp0 & 31);
      const u16* src = Bt + (size_t)(n0 + grow) * K + kb + ((sseg ^ (grow & 7)) << 3);
      u16* dst = &S[32768 + slot * 16384 + row0 * 64];
      gload16(src, dst);
    }
  };
  auto mmp = [&](int slot, int mp, int np){
    short8 a[4][2], b[2][2];
    #pragma unroll
    for (int mm = 0; mm < 4; mm++)
      #pragma unroll
      for (int kk = 0; kk < 2; kk++){
        const int row = wr * 128 + (mp * 4 + mm) * 16 + fr;
        a[mm][kk] = *(const short8*)&S[slot * 16384 + row * 64 + (((kk * 4 + q) ^ (row & 7)) << 3)];
      }
    #pragma unroll
    for (int nn = 0; nn < 2; nn++)
      #pragma unroll
      for (int kk = 0; kk < 2; kk++){
        const int row = wc * 64 + (np * 2 + nn) * 16 + fr;
        b[nn][kk] = *(const short8*)&S[32768 + slot * 16384 + row * 64 + (((kk * 4 + q) ^ (row & 7)) << 3)];
      }
    __builtin_amdgcn_s_setprio(1);
    #pragma unroll
    for (int mm = 0; mm < 4; mm++)
      #pragma unroll
      for (int nn = 0; nn < 2; nn++)
        #pragma unroll
        for (int kk = 0; kk < 2; kk++)
          acc[mp * 4 + mm][np * 2 + nn] = __builtin_amdgcn_mfma_f32_16x16x32_bf16(
              a[mm][kk], b[nn][kk], acc[mp * 4 + mm][np * 2 + nn], 0, 0, 0);
    __builtin_amdgcn_s_setprio(0);
  };

#define VMW(N) do { __builtin_amdgcn_sched_barrier(0); \
    asm volatile("s_waitcnt vmcnt(" #N ")" ::: "memory"); \
    __builtin_amdgcn_s_barrier(); \
    __builtin_amdgcn_sched_barrier(0); } while (0)

  // prologue: slot0 <- K-tile 0 (units in read order: A0,B0,A1,B1)
  stageA(0, 0, 0); stageB(0, 0, 0); stageA(0, 1, 0); stageB(0, 1, 0);
  const int niter = K >> 7;     // 2 K-tiles (128) per iteration
  #pragma unroll 1
  for (int t = 0; t < niter - 1; ++t){
    const int kb1 = (2 * t + 1) << 6, kb0 = (2 * t + 2) << 6;
    VMW(4); stageA(1, 0, kb1); mmp(0, 0, 0);
    VMW(4); stageB(1, 0, kb1); mmp(0, 1, 0);
    VMW(4); stageA(1, 1, kb1); mmp(0, 0, 1);
    VMW(4); stageB(1, 1, kb1); mmp(0, 1, 1);
    VMW(4); stageA(0, 0, kb0); mmp(1, 0, 0);
    VMW(4); stageB(0, 0, kb0); mmp(1, 1, 0);
    VMW(4); stageA(0, 1, kb0); mmp(1, 0, 1);
    VMW(4); stageB(0, 1, kb0); mmp(1, 1, 1);
  }
  { // last iteration: stage slot1 <- final K-tile, no slot0 refill; drain tail
    const int kb1 = (2 * niter - 1) << 6;
    VMW(4); stageA(1, 0, kb1); mmp(0, 0, 0);
    VMW(4); stageB(1, 0, kb1); mmp(0, 1, 0);
    VMW(4); stageA(1, 1, kb1); mmp(0, 0, 1);
    VMW(4); stageB(1, 1, kb1); mmp(0, 1, 1);
    VMW(4); mmp(1, 0, 0);
    VMW(2); mmp(1, 1, 0);
    VMW(0); mmp(1, 0, 1);
    __builtin_amdgcn_sched_barrier(0);
    __builtin_amdgcn_s_barrier();
    __builtin_amdgcn_sched_barrier(0);
    mmp(1, 1, 1);
  }
#undef VMW

  const int rg = q * 4;
  #pragma unroll
  for (int m = 0; m < 8; m++){
    #pragma unroll
    for (int n = 0; n < 4; n++){
      const int col = n0 + wc * 64 + n * 16 + fr;
      const float bv = BIAS ? bias[col] : 0.f;
      #pragma unroll
      for (int r = 0; r < 4; r++){
        const int row = m0 + wr * 128 + m * 16 + rg + r;
        float xv = acc[m][n][r] + bv;
        if (GELU) xv = 0.5f * xv * (1.f + erff(xv * 0.70710678118f));
        if (OBF16) ((u16*)Cv)[(size_t)row * ldc + col] = f2bf(xv);
        else       ((float*)Cv)[(size_t)row * ldc + col] = xv;
      }
    }
  }
}

// ---------------- 128x128 GEMM (final head matmul) ----------------
template<int OBF16, int BIAS, int GELU>
__global__ __launch_bounds__(256, 2) void gemm_bt(
    const u16* __restrict__ A, int lda,
    const u16* __restrict__ Bt,
    void* __restrict__ Cv, int ldc,
    const float* __restrict__ bias, int K)
{
  __shared__ u16 As[128 * 32];
  __shared__ u16 Bs[128 * 32];
  const int m0 = blockIdx.x * 128, n0 = blockIdx.y * 128;
  const int tid = threadIdx.x;
  const int l = tid & 63, w = tid >> 6;
  const int wr = w >> 1, wc = w & 1;
  f32x4 acc[4][4] = {};
  const int lr = l >> 2;
  const int lseg = (l & 3) * 8;
  u16* aB0 = &As[(w * 32) * 32];
  u16* aB1 = &As[(w * 32 + 16) * 32];
  u16* bB0 = &Bs[(w * 32) * 32];
  u16* bB1 = &Bs[(w * 32 + 16) * 32];
  const u16* ga0 = A + (size_t)(m0 + w * 32 + lr) * lda + lseg;
  const u16* ga1 = A + (size_t)(m0 + w * 32 + 16 + lr) * lda + lseg;
  const u16* gb0 = Bt + (size_t)(n0 + w * 32 + lr) * K + lseg;
  const u16* gb1 = Bt + (size_t)(n0 + w * 32 + 16 + lr) * K + lseg;
  const int fr = l & 15, kg = (l >> 4) * 8;
  for (int kt = 0; kt < K; kt += 32){
    __syncthreads();
    gload16(ga0 + kt, aB0);
    gload16(ga1 + kt, aB1);
    gload16(gb0 + kt, bB0);
    gload16(gb1 + kt, bB1);
    __syncthreads();
    short8 af[4], bf[4];
    #pragma unroll
    for (int i = 0; i < 4; i++){
      af[i] = *(const short8*)&As[(wr * 64 + i * 16 + fr) * 32 + kg];
      bf[i] = *(const short8*)&Bs[(wc * 64 + i * 16 + fr) * 32 + kg];
    }
    #pragma unroll
    for (int i = 0; i < 4; i++)
      #pragma unroll
      for (int j = 0; j < 4; j++)
        acc[i][j] = __builtin_amdgcn_mfma_f32_16x16x32_bf16(af[i], bf[j], acc[i][j], 0, 0, 0);
  }
  const int rg = (l >> 4) * 4;
  #pragma unroll
  for (int i = 0; i < 4; i++){
    #pragma unroll
    for (int j = 0; j < 4; j++){
      const int col = n0 + wc * 64 + j * 16 + fr;
      const float bv = BIAS ? bias[col] : 0.f;
      #pragma unroll
      for (int r = 0; r < 4; r++){
        const int row = m0 + wr * 64 + i * 16 + rg + r;
        float xv = acc[i][j][r] + bv;
        if (GELU) xv = 0.5f * xv * (1.f + erff(xv * 0.70710678118f));
        if (OBF16) ((u16*)Cv)[(size_t)row * ldc + col] = f2bf(xv);
        else       ((float*)Cv)[(size_t)row * ldc + col] = xv;
      }
    }
  }
}

extern "C" void kernel_launch(void* const* d_in, const int* in_sizes, int n_in,
                              void* d_out, int out_size, void* d_ws, size_t ws_size,
                              hipStream_t stream) {
  const int*   x       = (const int*)  d_in[0];
  const float* emb     = (const float*)d_in[1];
  const float* pool    = (const float*)d_in[2];
  const float* Wq      = (const float*)d_in[3];
  const float* Wk      = (const float*)d_in[4];
  const float* Wv      = (const float*)d_in[5];
  const float* Wo      = (const float*)d_in[6];
  const float* rel     = (const float*)d_in[7];
  const float* ln1_g   = (const float*)d_in[8];
  const float* ln1_b   = (const float*)d_in[9];
  const float* ln2_g   = (const float*)d_in[10];
  const float* ln2_b   = (const float*)d_in[11];
  const float* W1      = (const float*)d_in[12];
  const float* b1      = (const float*)d_in[13];
  const float* W2      = (const float*)d_in[14];
  const float* b2      = (const float*)d_in[15];
  const float* Wout    = (const float*)d_in[16];
  const float* bout    = (const float*)d_in[17];
  float* out = (float*)d_out;

  const size_t SZ_WDD  = (size_t)D * D * 2;
  const size_t SZ_WDF  = (size_t)D * DFF * 2;
  const size_t SZ_H    = (size_t)ROWS * D * 4;
  const size_t SZ_HB   = (size_t)ROWS * D * 2;
  const size_t need = 4*SZ_WDD + 3*SZ_WDF + SZ_H + SZ_HB + 4*SZ_HB + SZ_H;
  if (ws_size < need) return;

  char* p = (char*)d_ws;
  u16* WqkvT = (u16*)p; p += 3*SZ_WDD;
  u16* WoT   = (u16*)p; p += SZ_WDD;
  u16* W1T   = (u16*)p; p += SZ_WDF;
  u16* W2T   = (u16*)p; p += SZ_WDF;
  u16* WouT  = (u16*)p; p += SZ_WDF;
  float* h   = (float*)p; p += SZ_H;
  u16* hb    = (u16*)p; p += SZ_HB;
  u16* qkv   = (u16*)p; p += 3*SZ_HB;
  u16* ctxb  = (u16*)p; p += SZ_HB;
  u16* gb    = qkv;
  float* tmp = (float*)p; p += SZ_H;

  dim3 tb(32, 8);
  transpose_cast<<<dim3(VOCAB/32, D/32), tb, 0, stream>>>(Wout, WouT, D, VOCAB);
  embed_kernel<<<ROWS, 256, 0, stream>>>(x, emb, pool, h, hb);

  for (int l = 0; l < LAYERS; ++l){
    const size_t wo = (size_t)l * D * D;
    const size_t wf = (size_t)l * D * DFF;
    transpose_cast<<<dim3(D/32,   D/32),   tb, 0, stream>>>(Wq + wo, WqkvT,         D, D);
    transpose_cast<<<dim3(D/32,   D/32),   tb, 0, stream>>>(Wk + wo, WqkvT + D*D,   D, D);
    transpose_cast<<<dim3(D/32,   D/32),   tb, 0, stream>>>(Wv + wo, WqkvT + 2*D*D, D, D);
    transpose_cast<<<dim3(D/32,   D/32),   tb, 0, stream>>>(Wo + wo, WoT, D, D);
    transpose_cast<<<dim3(DFF/32, D/32),   tb, 0, stream>>>(W1 + wf, W1T, D, DFF);
    transpose_cast<<<dim3(D/32,   DFF/32), tb, 0, stream>>>(W2 + wf, W2T, DFF, D);

    gemm8p<1,0,0><<<dim3(ROWS/256, QS/256),  512, 0, stream>>>(hb, D, WqkvT, qkv, QS, nullptr, D);
    attn_kernel<<<BATCH*NH, 256, 0, stream>>>(qkv, rel + (size_t)l*NH*78*78, ctxb);
    gemm8p<0,0,0><<<dim3(ROWS/256, D/256),   512, 0, stream>>>(ctxb, D, WoT, tmp, D, nullptr, D);
    ln_kernel<<<ROWS, 256, 0, stream>>>(h, tmp, hb, ln1_g + l*D, ln1_b + l*D);
    gemm8p<1,1,1><<<dim3(ROWS/256, DFF/256), 512, 0, stream>>>(hb, D, W1T, gb, DFF, b1 + l*DFF, D);
    gemm8p<0,1,0><<<dim3(ROWS/256, D/256),   512, 0, stream>>>(gb, DFF, W2T, tmp, D, b2 + l*D, DFF);
    ln_kernel<<<ROWS, 256, 0, stream>>>(h, tmp, hb, ln2_g + l*D, ln2_b + l*D);
  }
  gemm_bt<0,1,0><<<dim3(BATCH/128, VOCAB/128), 256, 0, stream>>>(
      hb, TT * D, WouT, out, VOCAB, bout, D);
}

// Round 8
// 7983.129 us; speedup vs baseline: 1.0747x; 1.0460x over previous
//
#include <hip/hip_runtime.h>
#include <math.h>

typedef unsigned short u16;
typedef __attribute__((ext_vector_type(8))) short short8;
typedef __attribute__((ext_vector_type(4))) float f32x4;

#define LAYERS 8
#define D 1024
#define NH 16
#define DKH 64
#define DFF 4096
#define SEQ 66
#define TT 67
#define BATCH 256
#define ROWS (BATCH*TT)   /* 17152 = 67*256 */
#define VOCAB 4096
#define TP 80
#define KP 96
#define QS 3072           /* merged qkv row stride */

__device__ __forceinline__ float bf2f(u16 v){
  unsigned int u = ((unsigned int)v) << 16;
  return __builtin_bit_cast(float, u);
}
__device__ __forceinline__ u16 f2bf(float f){
  unsigned int u = __builtin_bit_cast(unsigned int, f);
  u += 0x7FFFu + ((u >> 16) & 1u);
  return (u16)(u >> 16);
}
__device__ __forceinline__ void gload16(const u16* g, u16* l){
  __builtin_amdgcn_global_load_lds((const __attribute__((address_space(1))) void*)g,
                                   (__attribute__((address_space(3))) void*)l, 16, 0, 0);
}

// ---------------- transpose + cast f32 -> bf16 ----------------
__global__ void transpose_cast(const float* __restrict__ src, u16* __restrict__ dst,
                               int R, int C){
  __shared__ float tile[32][33];
  const int c0 = blockIdx.x * 32, r0 = blockIdx.y * 32;
  const int tx = threadIdx.x, ty = threadIdx.y;
  #pragma unroll
  for (int i = 0; i < 32; i += 8)
    tile[ty + i][tx] = src[(size_t)(r0 + ty + i) * C + (c0 + tx)];
  __syncthreads();
  #pragma unroll
  for (int i = 0; i < 32; i += 8)
    dst[(size_t)(c0 + ty + i) * R + (r0 + tx)] = f2bf(tile[tx][ty + i]);
}

// ---------------- embedding + positional encoding ----------------
__global__ void embed_kernel(const int* __restrict__ x, const float* __restrict__ emb,
                             const float* __restrict__ pool, float* __restrict__ h,
                             u16* __restrict__ hb){
  const int row = blockIdx.x;
  const int b = row / TT, t = row % TT;
  const int d0 = threadIdx.x * 4;
  float v[4];
  if (t == 0){
    const float4 p4 = *(const float4*)&pool[d0];
    v[0] = p4.x; v[1] = p4.y; v[2] = p4.z; v[3] = p4.w;
  } else {
    const int id = x[b * SEQ + (t - 1)];
    const float4 e4 = *(const float4*)&emb[(size_t)id * D + d0];
    v[0] = e4.x * 32.f; v[1] = e4.y * 32.f; v[2] = e4.z * 32.f; v[3] = e4.w * 32.f;
  }
  const float c = -logf(10000.f) / (float)D;
  float o[4];
  #pragma unroll
  for (int j = 0; j < 4; j++){
    const int d = d0 + j;
    const int p = d >> 1;
    const float freq = expf((float)(2 * p) * c);
    const float ang = (float)t * freq;
    const float pe = (d & 1) ? cosf(ang) : sinf(ang);
    o[j] = v[j] + pe;
  }
  *(float4*)&h[(size_t)row * D + d0] = make_float4(o[0], o[1], o[2], o[3]);
  const unsigned int lo = (unsigned)f2bf(o[0]) | ((unsigned)f2bf(o[1]) << 16);
  const unsigned int hi = (unsigned)f2bf(o[2]) | ((unsigned)f2bf(o[3]) << 16);
  *(uint2*)&hb[(size_t)row * D + d0] = make_uint2(lo, hi);
}

// ---------------- fused residual + LayerNorm ----------------
__global__ void ln_kernel(float* __restrict__ h, const float* __restrict__ res,
                          u16* __restrict__ hb, const float* __restrict__ g,
                          const float* __restrict__ bta){
  const int row = blockIdx.x;
  const int tid = threadIdx.x;
  const size_t off = (size_t)row * D + tid * 4;
  const float4 a = *(const float4*)&h[off];
  const float4 r4 = *(const float4*)&res[off];
  const float s0 = a.x + r4.x, s1 = a.y + r4.y, s2 = a.z + r4.z, s3 = a.w + r4.w;
  float sum = s0 + s1 + s2 + s3;
  float sq = s0*s0 + s1*s1 + s2*s2 + s3*s3;
  #pragma unroll
  for (int m = 32; m >= 1; m >>= 1){ sum += __shfl_xor(sum, m); sq += __shfl_xor(sq, m); }
  __shared__ float red[2][4];
  const int w = tid >> 6;
  if ((tid & 63) == 0){ red[0][w] = sum; red[1][w] = sq; }
  __syncthreads();
  sum = red[0][0] + red[0][1] + red[0][2] + red[0][3];
  sq  = red[1][0] + red[1][1] + red[1][2] + red[1][3];
  const float mean = sum * (1.f / D);
  const float var = sq * (1.f / D) - mean * mean;
  const float rs = rsqrtf(var + 1e-5f);
  const float4 gv = *(const float4*)&g[tid * 4];
  const float4 bv = *(const float4*)&bta[tid * 4];
  const float o0 = (s0 - mean) * rs * gv.x + bv.x;
  const float o1 = (s1 - mean) * rs * gv.y + bv.y;
  const float o2 = (s2 - mean) * rs * gv.z + bv.z;
  const float o3 = (s3 - mean) * rs * gv.w + bv.w;
  *(float4*)&h[off] = make_float4(o0, o1, o2, o3);
  const unsigned int lo = (unsigned)f2bf(o0) | ((unsigned)f2bf(o1) << 16);
  const unsigned int hi = (unsigned)f2bf(o2) | ((unsigned)f2bf(o3) << 16);
  *(uint2*)&hb[off] = make_uint2(lo, hi);
}

// ---------------- MFMA attention: one block (4 waves) per (batch, head) ----------------
__global__ __launch_bounds__(256) void attn_kernel(const u16* __restrict__ qkv,
    const float* __restrict__ rel, u16* __restrict__ ctxb){
  __shared__ u16 Qf[8 * 81 * 8];
  __shared__ u16 Kf[8 * 81 * 8];
  __shared__ u16 Vf[12 * 65 * 8];
  __shared__ u16 Pf[12 * 81 * 8];
  __shared__ float Ss[TP][84];
  const int bh = blockIdx.x;
  const int b = bh >> 4, hh = bh & 15;
  const int tid = threadIdx.x, w = tid >> 6, l = tid & 63;
  const size_t qvbase = (size_t)(b * TT) * QS + hh * DKH;
  const size_t obase  = (size_t)(b * TT) * D + hh * DKH;

  {
    const int r0 = tid >> 4, c4 = (tid & 15) * 4;
    const int g = c4 >> 3, e = c4 & 7;
    for (int r = r0; r < TP; r += 16){
      uint2 q2 = make_uint2(0u, 0u), k2 = make_uint2(0u, 0u);
      if (r < TT){
        q2 = *(const uint2*)&qkv[qvbase + (size_t)r * QS + c4];
        k2 = *(const uint2*)&qkv[qvbase + 1024 + (size_t)r * QS + c4];
      }
      *(uint2*)&Qf[(g * 81 + r) * 8 + e] = q2;
      *(uint2*)&Kf[(g * 81 + r) * 8 + e] = k2;
    }
    for (int j = r0; j < KP; j += 16){
      u16 v4[4] = {0, 0, 0, 0};
      if (j < TT) *(uint2*)v4 = *(const uint2*)&qkv[qvbase + 2048 + (size_t)j * QS + c4];
      const int gg = j >> 3, ee = j & 7;
      #pragma unroll
      for (int d = 0; d < 4; d++)
        Vf[(gg * 65 + (c4 + d)) * 8 + ee] = v4[d];
    }
  }
  __syncthreads();

  const int fr = l & 15, gg = l >> 4;
  for (int p = w; p < 25; p += 4){
    const int rt = p / 5, ct = p % 5;
    f32x4 acc = {};
    #pragma unroll
    for (int kk = 0; kk < 2; kk++){
      const short8 a  = *(const short8*)&Qf[((kk * 4 + gg) * 81 + rt * 16 + fr) * 8];
      const short8 bf = *(const short8*)&Kf[((kk * 4 + gg) * 81 + ct * 16 + fr) * 8];
      acc = __builtin_amdgcn_mfma_f32_16x16x32_bf16(a, bf, acc, 0, 0, 0);
    }
    const int col = ct * 16 + fr;
    #pragma unroll
    for (int r = 0; r < 4; r++){
      const int row = rt * 16 + gg * 4 + r;
      float sv = -1e30f;
      if (row < TT && col < TT)
        sv = acc[r] * 0.125f + rel[((size_t)hh * 78 + row) * 78 + col];
      Ss[row][col] = sv;
    }
  }
  __syncthreads();

  for (int row = w; row < TP; row += 4){
    const float s1 = Ss[row][l];
    const float s2 = (l < 16) ? Ss[row][64 + l] : -1e30f;
    float mx = fmaxf(s1, s2);
    #pragma unroll
    for (int m = 32; m >= 1; m >>= 1) mx = fmaxf(mx, __shfl_xor(mx, m));
    const float e1 = __expf(s1 - mx);
    const float e2 = (l < 16) ? __expf(s2 - mx) : 0.f;
    float sum = e1 + e2;
    #pragma unroll
    for (int m = 32; m >= 1; m >>= 1) sum += __shfl_xor(sum, m);
    const float inv = 1.f / sum;
    Pf[((l >> 3) * 81 + row) * 8 + (l & 7)] = f2bf(e1 * inv);
    if (l < 16){
      Pf[((8  + (l >> 3)) * 81 + row) * 8 + (l & 7)] = f2bf(e2 * inv);
      Pf[((10 + (l >> 3)) * 81 + row) * 8 + (l & 7)] = 0;
    }
  }
  __syncthreads();

  for (int p = w; p < 20; p += 4){
    const int rt = p >> 2, ct = p & 3;
    f32x4 acc = {};
    #pragma unroll
    for (int kk = 0; kk < 3; kk++){
      const short8 a  = *(const short8*)&Pf[((kk * 4 + gg) * 81 + rt * 16 + fr) * 8];
      const short8 bf = *(const short8*)&Vf[((kk * 4 + gg) * 65 + ct * 16 + fr) * 8];
      acc = __builtin_amdgcn_mfma_f32_16x16x32_bf16(a, bf, acc, 0, 0, 0);
    }
    #pragma unroll
    for (int r = 0; r < 4; r++){
      const int row = rt * 16 + gg * 4 + r;
      if (row < TT)
        ctxb[obase + (size_t)row * D + ct * 16 + fr] = f2bf(acc[r]);
    }
  }
}

// ---------------- 256x256 bf16 MFMA GEMM — 8-phase, dedup'd fragment reads ----------------
// 8 waves (2Mx4N), BK=64, dbuf slots, 128KB LDS. Per K-tile (4 phases):
//   q0: vmcnt(2)+bar | stage A0' | read B all (8 b128, HELD) + A m-pair0 (4) | 16 MFMA
//   q1: vmcnt(4)+bar | stage B0' | read A m-pair1 (4) | 16 MFMA   (B reused from regs)
//   q2: vmcnt(4)+bar | stage B1' | read A m-pair2 (4) | 16 MFMA
//   q3: vmcnt(4)+bar | stage A1' | read A m-pair3 (4) | 16 MFMA
// 24 ds_read_b128 per K-tile per wave (minimum for 128x64/wave tiling).
// LDS [256][64] linear; T2 swizzle: 16B-unit ^= row&7 on source AND read.
template<int OBF16, int BIAS, int GELU>
__global__ __launch_bounds__(512, 2) void gemm8p(
    const u16* __restrict__ A, int lda,
    const u16* __restrict__ Bt,
    void* __restrict__ Cv, int ldc,
    const float* __restrict__ bias, int K)
{
  __shared__ u16 S[65536];   // A: [2][256][64] at 0; B: [2][256][64] at 32768
  const int tid = threadIdx.x, l = tid & 63, w = tid >> 6;
  const int wr = w >> 2, wc = w & 3;
  const int m0 = blockIdx.x * 256, n0 = blockIdx.y * 256;
  const int fr = l & 15, q = l >> 4;
  const int srw = tid >> 3, sseg = tid & 7;   // stage: row-in-64 (0..63), 16B-seg (0..7)
  const int wub = srw & 56;                   // wave-uniform row base (w*8)
  f32x4 acc[8][4] = {};
  short8 b[4][2];

  auto stageA = [&](int slot, int mp, int kb){
    #pragma unroll
    for (int j = 0; j < 2; j++){
      const int rb = j * 128 + mp * 64;
      const int grow = rb + srw;
      const u16* src = A + (size_t)(m0 + grow) * lda + kb + ((sseg ^ (grow & 7)) << 3);
      u16* dst = &S[slot * 16384 + (rb + wub) * 64];
      gload16(src, dst);
    }
  };
  auto stageB = [&](int slot, int np, int kb){
    #pragma unroll
    for (int j = 0; j < 2; j++){
      const int rp = j * 64 + srw;
      const int grow = ((rp >> 5) << 6) + np * 32 + (rp & 31);
      const int rp0 = j * 64 + wub;
      const int row0 = ((rp0 >> 5) << 6) + np * 32 + (rp0 & 31);
      const u16* src = Bt + (size_t)(n0 + grow) * K + kb + ((sseg ^ (grow & 7)) << 3);
      u16* dst = &S[32768 + slot * 16384 + row0 * 64];
      gload16(src, dst);
    }
  };
  auto rdA = [&](int slot, int m, int kk)->short8{
    const int row = wr * 128 + m * 16 + fr;
    return *(const short8*)&S[slot * 16384 + row * 64 + (((kk * 4 + q) ^ (row & 7)) << 3)];
  };
  auto rdB = [&](int slot, int n, int kk)->short8{
    const int row = wc * 64 + n * 16 + fr;
    return *(const short8*)&S[32768 + slot * 16384 + row * 64 + (((kk * 4 + q) ^ (row & 7)) << 3)];
  };

#define MFMA_(a_, b_, c_) __builtin_amdgcn_mfma_f32_16x16x32_bf16(a_, b_, c_, 0, 0, 0)
#define MP(s_, MPi) do { \
    const short8 a0k0 = rdA(s_, 2*MPi,   0), a0k1 = rdA(s_, 2*MPi,   1); \
    const short8 a1k0 = rdA(s_, 2*MPi+1, 0), a1k1 = rdA(s_, 2*MPi+1, 1); \
    __builtin_amdgcn_s_setprio(1); \
    _Pragma("unroll") \
    for (int n = 0; n < 4; n++){ \
      acc[2*MPi][n]   = MFMA_(a0k0, b[n][0], acc[2*MPi][n]); \
      acc[2*MPi][n]   = MFMA_(a0k1, b[n][1], acc[2*MPi][n]); \
      acc[2*MPi+1][n] = MFMA_(a1k0, b[n][0], acc[2*MPi+1][n]); \
      acc[2*MPi+1][n] = MFMA_(a1k1, b[n][1], acc[2*MPi+1][n]); \
    } \
    __builtin_amdgcn_s_setprio(0); \
  } while (0)

#define VMW(N) do { __builtin_amdgcn_sched_barrier(0); \
    asm volatile("s_waitcnt vmcnt(" #N ")" ::: "memory"); \
    __builtin_amdgcn_s_barrier(); \
    __builtin_amdgcn_sched_barrier(0); } while (0)

#define LDB8(s_) do { \
    b[0][0]=rdB(s_,0,0); b[0][1]=rdB(s_,0,1); b[1][0]=rdB(s_,1,0); b[1][1]=rdB(s_,1,1); \
    b[2][0]=rdB(s_,2,0); b[2][1]=rdB(s_,2,1); b[3][0]=rdB(s_,3,0); b[3][1]=rdB(s_,3,1); \
  } while (0)

// GROUP: consume slot s_; stage next tile (kbn) into slot s_^1 in order A0,B0,B1,A1
#define GROUP(s_, stg_, kbn, V0, V1, V2, V3) do { \
    VMW(V0); if (stg_) stageA((s_)^1, 0, kbn); LDB8(s_); MP(s_, 0); \
    VMW(V1); if (stg_) stageB((s_)^1, 0, kbn); MP(s_, 1); \
    VMW(V2); if (stg_) stageB((s_)^1, 1, kbn); MP(s_, 2); \
    VMW(V3); if (stg_) stageA((s_)^1, 1, kbn); MP(s_, 3); \
  } while (0)

  // prologue: slot0 <- K-tile 0, stage order A0,B0,B1,A1
  stageA(0, 0, 0); stageB(0, 0, 0); stageB(0, 1, 0); stageA(0, 1, 0);
  const int niter = K >> 7;     // 2 K-tiles (128) per iteration
  #pragma unroll 1
  for (int t = 0; t < niter - 1; ++t){
    const int kb1 = (2 * t + 1) << 6, kb0 = (2 * t + 2) << 6;
    GROUP(0, 1, kb1, 2, 4, 4, 4);
    GROUP(1, 1, kb0, 2, 4, 4, 4);
  }
  {
    const int kb1 = (2 * niter - 1) << 6;
    GROUP(0, 1, kb1, 2, 4, 4, 4);
    GROUP(1, 0, 0,   2, 2, 0, 0);   // tail: no staging, drain
  }
#undef GROUP
#undef LDB8
#undef VMW
#undef MP
#undef MFMA_

  const int rg = q * 4;
  #pragma unroll
  for (int m = 0; m < 8; m++){
    #pragma unroll
    for (int n = 0; n < 4; n++){
      const int col = n0 + wc * 64 + n * 16 + fr;
      const float bv = BIAS ? bias[col] : 0.f;
      #pragma unroll
      for (int r = 0; r < 4; r++){
        const int row = m0 + wr * 128 + m * 16 + rg + r;
        float xv = acc[m][n][r] + bv;
        if (GELU) xv = 0.5f * xv * (1.f + erff(xv * 0.70710678118f));
        if (OBF16) ((u16*)Cv)[(size_t)row * ldc + col] = f2bf(xv);
        else       ((float*)Cv)[(size_t)row * ldc + col] = xv;
      }
    }
  }
}

// ---------------- 128x128 GEMM (final head matmul) ----------------
template<int OBF16, int BIAS, int GELU>
__global__ __launch_bounds__(256, 2) void gemm_bt(
    const u16* __restrict__ A, int lda,
    const u16* __restrict__ Bt,
    void* __restrict__ Cv, int ldc,
    const float* __restrict__ bias, int K)
{
  __shared__ u16 As[128 * 32];
  __shared__ u16 Bs[128 * 32];
  const int m0 = blockIdx.x * 128, n0 = blockIdx.y * 128;
  const int tid = threadIdx.x;
  const int l = tid & 63, w = tid >> 6;
  const int wr = w >> 1, wc = w & 1;
  f32x4 acc[4][4] = {};
  const int lr = l >> 2;
  const int lseg = (l & 3) * 8;
  u16* aB0 = &As[(w * 32) * 32];
  u16* aB1 = &As[(w * 32 + 16) * 32];
  u16* bB0 = &Bs[(w * 32) * 32];
  u16* bB1 = &Bs[(w * 32 + 16) * 32];
  const u16* ga0 = A + (size_t)(m0 + w * 32 + lr) * lda + lseg;
  const u16* ga1 = A + (size_t)(m0 + w * 32 + 16 + lr) * lda + lseg;
  const u16* gb0 = Bt + (size_t)(n0 + w * 32 + lr) * K + lseg;
  const u16* gb1 = Bt + (size_t)(n0 + w * 32 + 16 + lr) * K + lseg;
  const int fr = l & 15, kg = (l >> 4) * 8;
  for (int kt = 0; kt < K; kt += 32){
    __syncthreads();
    gload16(ga0 + kt, aB0);
    gload16(ga1 + kt, aB1);
    gload16(gb0 + kt, bB0);
    gload16(gb1 + kt, bB1);
    __syncthreads();
    short8 af[4], bf[4];
    #pragma unroll
    for (int i = 0; i < 4; i++){
      af[i] = *(const short8*)&As[(wr * 64 + i * 16 + fr) * 32 + kg];
      bf[i] = *(const short8*)&Bs[(wc * 64 + i * 16 + fr) * 32 + kg];
    }
    #pragma unroll
    for (int i = 0; i < 4; i++)
      #pragma unroll
      for (int j = 0; j < 4; j++)
        acc[i][j] = __builtin_amdgcn_mfma_f32_16x16x32_bf16(af[i], bf[j], acc[i][j], 0, 0, 0);
  }
  const int rg = (l >> 4) * 4;
  #pragma unroll
  for (int i = 0; i < 4; i++){
    #pragma unroll
    for (int j = 0; j < 4; j++){
      const int col = n0 + wc * 64 + j * 16 + fr;
      const float bv = BIAS ? bias[col] : 0.f;
      #pragma unroll
      for (int r = 0; r < 4; r++){
        const int row = m0 + wr * 64 + i * 16 + rg + r;
        float xv = acc[i][j][r] + bv;
        if (GELU) xv = 0.5f * xv * (1.f + erff(xv * 0.70710678118f));
        if (OBF16) ((u16*)Cv)[(size_t)row * ldc + col] = f2bf(xv);
        else       ((float*)Cv)[(size_t)row * ldc + col] = xv;
      }
    }
  }
}

extern "C" void kernel_launch(void* const* d_in, const int* in_sizes, int n_in,
                              void* d_out, int out_size, void* d_ws, size_t ws_size,
                              hipStream_t stream) {
  const int*   x       = (const int*)  d_in[0];
  const float* emb     = (const float*)d_in[1];
  const float* pool    = (const float*)d_in[2];
  const float* Wq      = (const float*)d_in[3];
  const float* Wk      = (const float*)d_in[4];
  const float* Wv      = (const float*)d_in[5];
  const float* Wo      = (const float*)d_in[6];
  const float* rel     = (const float*)d_in[7];
  const float* ln1_g   = (const float*)d_in[8];
  const float* ln1_b   = (const float*)d_in[9];
  const float* ln2_g   = (const float*)d_in[10];
  const float* ln2_b   = (const float*)d_in[11];
  const float* W1      = (const float*)d_in[12];
  const float* b1      = (const float*)d_in[13];
  const float* W2      = (const float*)d_in[14];
  const float* b2      = (const float*)d_in[15];
  const float* Wout    = (const float*)d_in[16];
  const float* bout    = (const float*)d_in[17];
  float* out = (float*)d_out;

  const size_t SZ_WDD  = (size_t)D * D * 2;
  const size_t SZ_WDF  = (size_t)D * DFF * 2;
  const size_t SZ_H    = (size_t)ROWS * D * 4;
  const size_t SZ_HB   = (size_t)ROWS * D * 2;
  const size_t need = 4*SZ_WDD + 3*SZ_WDF + SZ_H + SZ_HB + 4*SZ_HB + SZ_H;
  if (ws_size < need) return;

  char* p = (char*)d_ws;
  u16* WqkvT = (u16*)p; p += 3*SZ_WDD;
  u16* WoT   = (u16*)p; p += SZ_WDD;
  u16* W1T   = (u16*)p; p += SZ_WDF;
  u16* W2T   = (u16*)p; p += SZ_WDF;
  u16* WouT  = (u16*)p; p += SZ_WDF;
  float* h   = (float*)p; p += SZ_H;
  u16* hb    = (u16*)p; p += SZ_HB;
  u16* qkv   = (u16*)p; p += 3*SZ_HB;
  u16* ctxb  = (u16*)p; p += SZ_HB;
  u16* gb    = qkv;
  float* tmp = (float*)p; p += SZ_H;

  dim3 tb(32, 8);
  transpose_cast<<<dim3(VOCAB/32, D/32), tb, 0, stream>>>(Wout, WouT, D, VOCAB);
  embed_kernel<<<ROWS, 256, 0, stream>>>(x, emb, pool, h, hb);

  for (int l = 0; l < LAYERS; ++l){
    const size_t wo = (size_t)l * D * D;
    const size_t wf = (size_t)l * D * DFF;
    transpose_cast<<<dim3(D/32,   D/32),   tb, 0, stream>>>(Wq + wo, WqkvT,         D, D);
    transpose_cast<<<dim3(D/32,   D/32),   tb, 0, stream>>>(Wk + wo, WqkvT + D*D,   D, D);
    transpose_cast<<<dim3(D/32,   D/32),   tb, 0, stream>>>(Wv + wo, WqkvT + 2*D*D, D, D);
    transpose_cast<<<dim3(D/32,   D/32),   tb, 0, stream>>>(Wo + wo, WoT, D, D);
    transpose_cast<<<dim3(DFF/32, D/32),   tb, 0, stream>>>(W1 + wf, W1T, D, DFF);
    transpose_cast<<<dim3(D/32,   DFF/32), tb, 0, stream>>>(W2 + wf, W2T, DFF, D);

    gemm8p<1,0,0><<<dim3(ROWS/256, QS/256),  512, 0, stream>>>(hb, D, WqkvT, qkv, QS, nullptr, D);
    attn_kernel<<<BATCH*NH, 256, 0, stream>>>(qkv, rel + (size_t)l*NH*78*78, ctxb);
    gemm8p<0,0,0><<<dim3(ROWS/256, D/256),   512, 0, stream>>>(ctxb, D, WoT, tmp, D, nullptr, D);
    ln_kernel<<<ROWS, 256, 0, stream>>>(h, tmp, hb, ln1_g + l*D, ln1_b + l*D);
    gemm8p<1,1,1><<<dim3(ROWS/256, DFF/256), 512, 0, stream>>>(hb, D, W1T, gb, DFF, b1 + l*DFF, D);
    gemm8p<0,1,0><<<dim3(ROWS/256, D/256),   512, 0, stream>>>(gb, DFF, W2T, tmp, D, b2 + l*D, DFF);
    ln_kernel<<<ROWS, 256, 0, stream>>>(h, tmp, hb, ln2_g + l*D, ln2_b + l*D);
  }
  gemm_bt<0,1,0><<<dim3(BATCH/128, VOCAB/128), 256, 0, stream>>>(
      hb, TT * D, WouT, out, VOCAB, bout, D);
}

// Round 9
// 7012.866 us; speedup vs baseline: 1.2234x; 1.1384x over previous
//
#include <hip/hip_runtime.h>
#include <math.h>

typedef unsigned short u16;
typedef __attribute__((ext_vector_type(8))) short short8;
typedef __attribute__((ext_vector_type(4))) float f32x4;

#define LAYERS 8
#define D 1024
#define NH 16
#define DKH 64
#define DFF 4096
#define SEQ 66
#define TT 67
#define BATCH 256
#define ROWS (BATCH*TT)   /* 17152 = 134*128 */
#define VOCAB 4096
#define TP 80
#define KP 96
#define QS 3072           /* merged qkv row stride */

__device__ __forceinline__ float bf2f(u16 v){
  unsigned int u = ((unsigned int)v) << 16;
  return __builtin_bit_cast(float, u);
}
__device__ __forceinline__ u16 f2bf(float f){
  unsigned int u = __builtin_bit_cast(unsigned int, f);
  u += 0x7FFFu + ((u >> 16) & 1u);
  return (u16)(u >> 16);
}
__device__ __forceinline__ void gload16(const u16* g, u16* l){
  __builtin_amdgcn_global_load_lds((const __attribute__((address_space(1))) void*)g,
                                   (__attribute__((address_space(3))) void*)l, 16, 0, 0);
}

// ---------------- transpose + cast f32 -> bf16 ----------------
__global__ void transpose_cast(const float* __restrict__ src, u16* __restrict__ dst,
                               int R, int C){
  __shared__ float tile[32][33];
  const int c0 = blockIdx.x * 32, r0 = blockIdx.y * 32;
  const int tx = threadIdx.x, ty = threadIdx.y;
  #pragma unroll
  for (int i = 0; i < 32; i += 8)
    tile[ty + i][tx] = src[(size_t)(r0 + ty + i) * C + (c0 + tx)];
  __syncthreads();
  #pragma unroll
  for (int i = 0; i < 32; i += 8)
    dst[(size_t)(c0 + ty + i) * R + (r0 + tx)] = f2bf(tile[tx][ty + i]);
}

// ---------------- embedding + positional encoding ----------------
__global__ void embed_kernel(const int* __restrict__ x, const float* __restrict__ emb,
                             const float* __restrict__ pool, float* __restrict__ h,
                             u16* __restrict__ hb){
  const int row = blockIdx.x;
  const int b = row / TT, t = row % TT;
  const int d0 = threadIdx.x * 4;
  float v[4];
  if (t == 0){
    const float4 p4 = *(const float4*)&pool[d0];
    v[0] = p4.x; v[1] = p4.y; v[2] = p4.z; v[3] = p4.w;
  } else {
    const int id = x[b * SEQ + (t - 1)];
    const float4 e4 = *(const float4*)&emb[(size_t)id * D + d0];
    v[0] = e4.x * 32.f; v[1] = e4.y * 32.f; v[2] = e4.z * 32.f; v[3] = e4.w * 32.f;
  }
  const float c = -logf(10000.f) / (float)D;
  float o[4];
  #pragma unroll
  for (int j = 0; j < 4; j++){
    const int d = d0 + j;
    const int p = d >> 1;
    const float freq = expf((float)(2 * p) * c);
    const float ang = (float)t * freq;
    const float pe = (d & 1) ? cosf(ang) : sinf(ang);
    o[j] = v[j] + pe;
  }
  *(float4*)&h[(size_t)row * D + d0] = make_float4(o[0], o[1], o[2], o[3]);
  const unsigned int lo = (unsigned)f2bf(o[0]) | ((unsigned)f2bf(o[1]) << 16);
  const unsigned int hi = (unsigned)f2bf(o[2]) | ((unsigned)f2bf(o[3]) << 16);
  *(uint2*)&hb[(size_t)row * D + d0] = make_uint2(lo, hi);
}

// ---------------- fused residual + LayerNorm ----------------
__global__ void ln_kernel(float* __restrict__ h, const float* __restrict__ res,
                          u16* __restrict__ hb, const float* __restrict__ g,
                          const float* __restrict__ bta){
  const int row = blockIdx.x;
  const int tid = threadIdx.x;
  const size_t off = (size_t)row * D + tid * 4;
  const float4 a = *(const float4*)&h[off];
  const float4 r4 = *(const float4*)&res[off];
  const float s0 = a.x + r4.x, s1 = a.y + r4.y, s2 = a.z + r4.z, s3 = a.w + r4.w;
  float sum = s0 + s1 + s2 + s3;
  float sq = s0*s0 + s1*s1 + s2*s2 + s3*s3;
  #pragma unroll
  for (int m = 32; m >= 1; m >>= 1){ sum += __shfl_xor(sum, m); sq += __shfl_xor(sq, m); }
  __shared__ float red[2][4];
  const int w = tid >> 6;
  if ((tid & 63) == 0){ red[0][w] = sum; red[1][w] = sq; }
  __syncthreads();
  sum = red[0][0] + red[0][1] + red[0][2] + red[0][3];
  sq  = red[1][0] + red[1][1] + red[1][2] + red[1][3];
  const float mean = sum * (1.f / D);
  const float var = sq * (1.f / D) - mean * mean;
  const float rs = rsqrtf(var + 1e-5f);
  const float4 gv = *(const float4*)&g[tid * 4];
  const float4 bv = *(const float4*)&bta[tid * 4];
  const float o0 = (s0 - mean) * rs * gv.x + bv.x;
  const float o1 = (s1 - mean) * rs * gv.y + bv.y;
  const float o2 = (s2 - mean) * rs * gv.z + bv.z;
  const float o3 = (s3 - mean) * rs * gv.w + bv.w;
  *(float4*)&h[off] = make_float4(o0, o1, o2, o3);
  const unsigned int lo = (unsigned)f2bf(o0) | ((unsigned)f2bf(o1) << 16);
  const unsigned int hi = (unsigned)f2bf(o2) | ((unsigned)f2bf(o3) << 16);
  *(uint2*)&hb[off] = make_uint2(lo, hi);
}

// ---------------- MFMA attention: one block (4 waves) per (batch, head) ----------------
__global__ __launch_bounds__(256) void attn_kernel(const u16* __restrict__ qkv,
    const float* __restrict__ rel, u16* __restrict__ ctxb){
  __shared__ u16 Qf[8 * 81 * 8];
  __shared__ u16 Kf[8 * 81 * 8];
  __shared__ u16 Vf[12 * 65 * 8];
  __shared__ u16 Pf[12 * 81 * 8];
  __shared__ float Ss[TP][84];
  const int bh = blockIdx.x;
  const int b = bh >> 4, hh = bh & 15;
  const int tid = threadIdx.x, w = tid >> 6, l = tid & 63;
  const size_t qvbase = (size_t)(b * TT) * QS + hh * DKH;
  const size_t obase  = (size_t)(b * TT) * D + hh * DKH;

  {
    const int r0 = tid >> 4, c4 = (tid & 15) * 4;
    const int g = c4 >> 3, e = c4 & 7;
    for (int r = r0; r < TP; r += 16){
      uint2 q2 = make_uint2(0u, 0u), k2 = make_uint2(0u, 0u);
      if (r < TT){
        q2 = *(const uint2*)&qkv[qvbase + (size_t)r * QS + c4];
        k2 = *(const uint2*)&qkv[qvbase + 1024 + (size_t)r * QS + c4];
      }
      *(uint2*)&Qf[(g * 81 + r) * 8 + e] = q2;
      *(uint2*)&Kf[(g * 81 + r) * 8 + e] = k2;
    }
    for (int j = r0; j < KP; j += 16){
      u16 v4[4] = {0, 0, 0, 0};
      if (j < TT) *(uint2*)v4 = *(const uint2*)&qkv[qvbase + 2048 + (size_t)j * QS + c4];
      const int gg = j >> 3, ee = j & 7;
      #pragma unroll
      for (int d = 0; d < 4; d++)
        Vf[(gg * 65 + (c4 + d)) * 8 + ee] = v4[d];
    }
  }
  __syncthreads();

  const int fr = l & 15, gg = l >> 4;
  for (int p = w; p < 25; p += 4){
    const int rt = p / 5, ct = p % 5;
    f32x4 acc = {};
    #pragma unroll
    for (int kk = 0; kk < 2; kk++){
      const short8 a  = *(const short8*)&Qf[((kk * 4 + gg) * 81 + rt * 16 + fr) * 8];
      const short8 bf = *(const short8*)&Kf[((kk * 4 + gg) * 81 + ct * 16 + fr) * 8];
      acc = __builtin_amdgcn_mfma_f32_16x16x32_bf16(a, bf, acc, 0, 0, 0);
    }
    const int col = ct * 16 + fr;
    #pragma unroll
    for (int r = 0; r < 4; r++){
      const int row = rt * 16 + gg * 4 + r;
      float sv = -1e30f;
      if (row < TT && col < TT)
        sv = acc[r] * 0.125f + rel[((size_t)hh * 78 + row) * 78 + col];
      Ss[row][col] = sv;
    }
  }
  __syncthreads();

  for (int row = w; row < TP; row += 4){
    const float s1 = Ss[row][l];
    const float s2 = (l < 16) ? Ss[row][64 + l] : -1e30f;
    float mx = fmaxf(s1, s2);
    #pragma unroll
    for (int m = 32; m >= 1; m >>= 1) mx = fmaxf(mx, __shfl_xor(mx, m));
    const float e1 = __expf(s1 - mx);
    const float e2 = (l < 16) ? __expf(s2 - mx) : 0.f;
    float sum = e1 + e2;
    #pragma unroll
    for (int m = 32; m >= 1; m >>= 1) sum += __shfl_xor(sum, m);
    const float inv = 1.f / sum;
    Pf[((l >> 3) * 81 + row) * 8 + (l & 7)] = f2bf(e1 * inv);
    if (l < 16){
      Pf[((8  + (l >> 3)) * 81 + row) * 8 + (l & 7)] = f2bf(e2 * inv);
      Pf[((10 + (l >> 3)) * 81 + row) * 8 + (l & 7)] = 0;
    }
  }
  __syncthreads();

  for (int p = w; p < 20; p += 4){
    const int rt = p >> 2, ct = p & 3;
    f32x4 acc = {};
    #pragma unroll
    for (int kk = 0; kk < 3; kk++){
      const short8 a  = *(const short8*)&Pf[((kk * 4 + gg) * 81 + rt * 16 + fr) * 8];
      const short8 bf = *(const short8*)&Vf[((kk * 4 + gg) * 65 + ct * 16 + fr) * 8];
      acc = __builtin_amdgcn_mfma_f32_16x16x32_bf16(a, bf, acc, 0, 0, 0);
    }
    #pragma unroll
    for (int r = 0; r < 4; r++){
      const int row = rt * 16 + gg * 4 + r;
      if (row < TT)
        ctxb[obase + (size_t)row * D + ct * 16 + fr] = f2bf(acc[r]);
    }
  }
}

// ---------------- 128x128 bf16 MFMA GEMM (gload_lds, 2-phase) with XCD-chunked,
// N-fast grid swizzle for L2 locality.  1-D grid of nbx*nby blocks.
// Each XCD gets a contiguous wg range; within it by varies fastest -> consecutive
// blocks share the A-panel (L2-resident) and stream B (L3-resident after 1st pass).
template<int OBF16, int BIAS, int GELU>
__global__ __launch_bounds__(256, 2) void gemm_bt(
    const u16* __restrict__ A, int lda,
    const u16* __restrict__ Bt,
    void* __restrict__ Cv, int ldc,
    const float* __restrict__ bias, int K, int nby)
{
  __shared__ u16 As[128 * 32];
  __shared__ u16 Bs[128 * 32];
  // bijective XCD-chunked swizzle (m204) + N-fast decode
  const int nwg = gridDim.x, bid = blockIdx.x;
  const int q8 = nwg >> 3, r8 = nwg & 7;
  const int xcd = bid & 7, off = bid >> 3;
  const int wg = (xcd < r8 ? xcd * (q8 + 1) : r8 * (q8 + 1) + (xcd - r8) * q8) + off;
  const int m0 = (wg / nby) * 128, n0 = (wg % nby) * 128;

  const int tid = threadIdx.x;
  const int l = tid & 63, w = tid >> 6;
  const int wr = w >> 1, wc = w & 1;
  f32x4 acc[4][4] = {};
  const int lr = l >> 2;
  const int lseg = (l & 3) * 8;
  u16* aB0 = &As[(w * 32) * 32];
  u16* aB1 = &As[(w * 32 + 16) * 32];
  u16* bB0 = &Bs[(w * 32) * 32];
  u16* bB1 = &Bs[(w * 32 + 16) * 32];
  const u16* ga0 = A + (size_t)(m0 + w * 32 + lr) * lda + lseg;
  const u16* ga1 = A + (size_t)(m0 + w * 32 + 16 + lr) * lda + lseg;
  const u16* gb0 = Bt + (size_t)(n0 + w * 32 + lr) * K + lseg;
  const u16* gb1 = Bt + (size_t)(n0 + w * 32 + 16 + lr) * K + lseg;
  const int fr = l & 15, kg = (l >> 4) * 8;
  for (int kt = 0; kt < K; kt += 32){
    __syncthreads();
    gload16(ga0 + kt, aB0);
    gload16(ga1 + kt, aB1);
    gload16(gb0 + kt, bB0);
    gload16(gb1 + kt, bB1);
    __syncthreads();
    short8 af[4], bf[4];
    #pragma unroll
    for (int i = 0; i < 4; i++){
      af[i] = *(const short8*)&As[(wr * 64 + i * 16 + fr) * 32 + kg];
      bf[i] = *(const short8*)&Bs[(wc * 64 + i * 16 + fr) * 32 + kg];
    }
    #pragma unroll
    for (int i = 0; i < 4; i++)
      #pragma unroll
      for (int j = 0; j < 4; j++)
        acc[i][j] = __builtin_amdgcn_mfma_f32_16x16x32_bf16(af[i], bf[j], acc[i][j], 0, 0, 0);
  }
  const int rg = (l >> 4) * 4;
  #pragma unroll
  for (int i = 0; i < 4; i++){
    #pragma unroll
    for (int j = 0; j < 4; j++){
      const int col = n0 + wc * 64 + j * 16 + fr;
      const float bv = BIAS ? bias[col] : 0.f;
      #pragma unroll
      for (int r = 0; r < 4; r++){
        const int row = m0 + wr * 64 + i * 16 + rg + r;
        float xv = acc[i][j][r] + bv;
        if (GELU) xv = 0.5f * xv * (1.f + erff(xv * 0.70710678118f));
        if (OBF16) ((u16*)Cv)[(size_t)row * ldc + col] = f2bf(xv);
        else       ((float*)Cv)[(size_t)row * ldc + col] = xv;
      }
    }
  }
}

extern "C" void kernel_launch(void* const* d_in, const int* in_sizes, int n_in,
                              void* d_out, int out_size, void* d_ws, size_t ws_size,
                              hipStream_t stream) {
  const int*   x       = (const int*)  d_in[0];
  const float* emb     = (const float*)d_in[1];
  const float* pool    = (const float*)d_in[2];
  const float* Wq      = (const float*)d_in[3];
  const float* Wk      = (const float*)d_in[4];
  const float* Wv      = (const float*)d_in[5];
  const float* Wo      = (const float*)d_in[6];
  const float* rel     = (const float*)d_in[7];
  const float* ln1_g   = (const float*)d_in[8];
  const float* ln1_b   = (const float*)d_in[9];
  const float* ln2_g   = (const float*)d_in[10];
  const float* ln2_b   = (const float*)d_in[11];
  const float* W1      = (const float*)d_in[12];
  const float* b1      = (const float*)d_in[13];
  const float* W2      = (const float*)d_in[14];
  const float* b2      = (const float*)d_in[15];
  const float* Wout    = (const float*)d_in[16];
  const float* bout    = (const float*)d_in[17];
  float* out = (float*)d_out;

  const size_t SZ_WDD  = (size_t)D * D * 2;
  const size_t SZ_WDF  = (size_t)D * DFF * 2;
  const size_t SZ_H    = (size_t)ROWS * D * 4;
  const size_t SZ_HB   = (size_t)ROWS * D * 2;
  const size_t need = 4*SZ_WDD + 3*SZ_WDF + SZ_H + SZ_HB + 4*SZ_HB + SZ_H;
  if (ws_size < need) return;

  char* p = (char*)d_ws;
  u16* WqkvT = (u16*)p; p += 3*SZ_WDD;   // rows [0,1024)=Wq^T, [1024,2048)=Wk^T, [2048,3072)=Wv^T
  u16* WoT   = (u16*)p; p += SZ_WDD;
  u16* W1T   = (u16*)p; p += SZ_WDF;
  u16* W2T   = (u16*)p; p += SZ_WDF;
  u16* WouT  = (u16*)p; p += SZ_WDF;
  float* h   = (float*)p; p += SZ_H;
  u16* hb    = (u16*)p; p += SZ_HB;
  u16* qkv   = (u16*)p; p += 3*SZ_HB;    // [ROWS][3072]
  u16* ctxb  = (u16*)p; p += SZ_HB;
  u16* gb    = qkv;                       // FFN hidden aliases qkv+ctx
  float* tmp = (float*)p; p += SZ_H;

  dim3 tb(32, 8);
  transpose_cast<<<dim3(VOCAB/32, D/32), tb, 0, stream>>>(Wout, WouT, D, VOCAB);
  embed_kernel<<<ROWS, 256, 0, stream>>>(x, emb, pool, h, hb);

  const int MB = ROWS / 128;   // 134
  for (int l = 0; l < LAYERS; ++l){
    const size_t wo = (size_t)l * D * D;
    const size_t wf = (size_t)l * D * DFF;
    transpose_cast<<<dim3(D/32,   D/32),   tb, 0, stream>>>(Wq + wo, WqkvT,         D, D);
    transpose_cast<<<dim3(D/32,   D/32),   tb, 0, stream>>>(Wk + wo, WqkvT + D*D,   D, D);
    transpose_cast<<<dim3(D/32,   D/32),   tb, 0, stream>>>(Wv + wo, WqkvT + 2*D*D, D, D);
    transpose_cast<<<dim3(D/32,   D/32),   tb, 0, stream>>>(Wo + wo, WoT, D, D);
    transpose_cast<<<dim3(DFF/32, D/32),   tb, 0, stream>>>(W1 + wf, W1T, D, DFF);
    transpose_cast<<<dim3(D/32,   DFF/32), tb, 0, stream>>>(W2 + wf, W2T, DFF, D);

    gemm_bt<1,0,0><<<MB * (QS/128),  256, 0, stream>>>(hb, D, WqkvT, qkv, QS, nullptr, D, QS/128);
    attn_kernel<<<BATCH*NH, 256, 0, stream>>>(qkv, rel + (size_t)l*NH*78*78, ctxb);
    gemm_bt<0,0,0><<<MB * (D/128),   256, 0, stream>>>(ctxb, D, WoT, tmp, D, nullptr, D, D/128);
    ln_kernel<<<ROWS, 256, 0, stream>>>(h, tmp, hb, ln1_g + l*D, ln1_b + l*D);
    gemm_bt<1,1,1><<<MB * (DFF/128), 256, 0, stream>>>(hb, D, W1T, gb, DFF, b1 + l*DFF, D, DFF/128);
    gemm_bt<0,1,0><<<MB * (D/128),   256, 0, stream>>>(gb, DFF, W2T, tmp, D, b2 + l*D, DFF, D/128);
    ln_kernel<<<ROWS, 256, 0, stream>>>(h, tmp, hb, ln2_g + l*D, ln2_b + l*D);
  }
  gemm_bt<0,1,0><<<(BATCH/128) * (VOCAB/128), 256, 0, stream>>>(
      hb, TT * D, WouT, out, VOCAB, bout, D, VOCAB/128);
}

// Round 10
// 6655.502 us; speedup vs baseline: 1.2891x; 1.0537x over previous
//
#include <hip/hip_runtime.h>
#include <math.h>

typedef unsigned short u16;
typedef __attribute__((ext_vector_type(8))) short short8;
typedef __attribute__((ext_vector_type(4))) float f32x4;

#define LAYERS 8
#define D 1024
#define NH 16
#define DKH 64
#define DFF 4096
#define SEQ 66
#define TT 67
#define BATCH 256
#define ROWS (BATCH*TT)   /* 17152 = 134*128 */
#define VOCAB 4096
#define TP 80
#define KP 96
#define QS 3072           /* merged qkv row stride */

__device__ __forceinline__ float bf2f(u16 v){
  unsigned int u = ((unsigned int)v) << 16;
  return __builtin_bit_cast(float, u);
}
__device__ __forceinline__ u16 f2bf(float f){
  unsigned int u = __builtin_bit_cast(unsigned int, f);
  u += 0x7FFFu + ((u >> 16) & 1u);
  return (u16)(u >> 16);
}
__device__ __forceinline__ void gload16(const u16* g, u16* l){
  __builtin_amdgcn_global_load_lds((const __attribute__((address_space(1))) void*)g,
                                   (__attribute__((address_space(3))) void*)l, 16, 0, 0);
}

// ---------------- transpose + cast f32 -> bf16, all 6 weights of a layer ----------------
__device__ __forceinline__ void tc_tile(const float* __restrict__ src, u16* __restrict__ dst,
                                        int R, int C, int bx, int by, int tx, int ty){
  __shared__ float tile[32][33];
  const int c0 = bx * 32, r0 = by * 32;
  #pragma unroll
  for (int i = 0; i < 32; i += 8)
    tile[ty + i][tx] = src[(size_t)(r0 + ty + i) * C + (c0 + tx)];
  __syncthreads();
  #pragma unroll
  for (int i = 0; i < 32; i += 8)
    dst[(size_t)(c0 + ty + i) * R + (r0 + tx)] = f2bf(tile[tx][ty + i]);
}

__global__ void transpose6(const float* __restrict__ Wq, const float* __restrict__ Wk,
                           const float* __restrict__ Wv, const float* __restrict__ Wo,
                           const float* __restrict__ W1, const float* __restrict__ W2,
                           u16* __restrict__ WqkvT, u16* __restrict__ WoT,
                           u16* __restrict__ W1T, u16* __restrict__ W2T){
  const int tx = threadIdx.x, ty = threadIdx.y;
  int b = blockIdx.x;
  if (b < 4096){                       // Wq/Wk/Wv/Wo : 1024 blocks each, 32x32 grid
    const int which = b >> 10, idx = b & 1023;
    const float* s = which == 0 ? Wq : which == 1 ? Wk : which == 2 ? Wv : Wo;
    u16* d = which == 3 ? WoT : WqkvT + which * D * D;
    tc_tile(s, d, D, D, idx & 31, idx >> 5, tx, ty);
  } else if (b < 8192){                // W1: (DFF/32) x (D/32) = 128 x 32
    const int idx = b - 4096;
    tc_tile(W1, W1T, D, DFF, idx & 127, idx >> 7, tx, ty);
  } else {                             // W2: (D/32) x (DFF/32) = 32 x 128
    const int idx = b - 8192;
    tc_tile(W2, W2T, DFF, D, idx & 31, idx >> 5, tx, ty);
  }
}

__global__ void transpose_cast(const float* __restrict__ src, u16* __restrict__ dst,
                               int R, int C){
  tc_tile(src, dst, R, C, blockIdx.x, blockIdx.y, threadIdx.x, threadIdx.y);
}

// ---------------- embedding + positional encoding ----------------
__global__ void embed_kernel(const int* __restrict__ x, const float* __restrict__ emb,
                             const float* __restrict__ pool, float* __restrict__ h,
                             u16* __restrict__ hb){
  const int row = blockIdx.x;
  const int b = row / TT, t = row % TT;
  const int d0 = threadIdx.x * 4;
  float v[4];
  if (t == 0){
    const float4 p4 = *(const float4*)&pool[d0];
    v[0] = p4.x; v[1] = p4.y; v[2] = p4.z; v[3] = p4.w;
  } else {
    const int id = x[b * SEQ + (t - 1)];
    const float4 e4 = *(const float4*)&emb[(size_t)id * D + d0];
    v[0] = e4.x * 32.f; v[1] = e4.y * 32.f; v[2] = e4.z * 32.f; v[3] = e4.w * 32.f;
  }
  const float c = -logf(10000.f) / (float)D;
  float o[4];
  #pragma unroll
  for (int j = 0; j < 4; j++){
    const int d = d0 + j;
    const int p = d >> 1;
    const float freq = expf((float)(2 * p) * c);
    const float ang = (float)t * freq;
    const float pe = (d & 1) ? cosf(ang) : sinf(ang);
    o[j] = v[j] + pe;
  }
  *(float4*)&h[(size_t)row * D + d0] = make_float4(o[0], o[1], o[2], o[3]);
  const unsigned int lo = (unsigned)f2bf(o[0]) | ((unsigned)f2bf(o[1]) << 16);
  const unsigned int hi = (unsigned)f2bf(o[2]) | ((unsigned)f2bf(o[3]) << 16);
  *(uint2*)&hb[(size_t)row * D + d0] = make_uint2(lo, hi);
}

// ---------------- fused residual + LayerNorm (residual branch now bf16) ----------------
__global__ void ln_kernel(float* __restrict__ h, const u16* __restrict__ res,
                          u16* __restrict__ hb, const float* __restrict__ g,
                          const float* __restrict__ bta){
  const int row = blockIdx.x;
  const int tid = threadIdx.x;
  const size_t off = (size_t)row * D + tid * 4;
  const float4 a = *(const float4*)&h[off];
  const uint2 r2 = *(const uint2*)&res[off];
  const float s0 = a.x + bf2f((u16)(r2.x & 0xffff));
  const float s1 = a.y + bf2f((u16)(r2.x >> 16));
  const float s2 = a.z + bf2f((u16)(r2.y & 0xffff));
  const float s3 = a.w + bf2f((u16)(r2.y >> 16));
  float sum = s0 + s1 + s2 + s3;
  float sq = s0*s0 + s1*s1 + s2*s2 + s3*s3;
  #pragma unroll
  for (int m = 32; m >= 1; m >>= 1){ sum += __shfl_xor(sum, m); sq += __shfl_xor(sq, m); }
  __shared__ float red[2][4];
  const int w = tid >> 6;
  if ((tid & 63) == 0){ red[0][w] = sum; red[1][w] = sq; }
  __syncthreads();
  sum = red[0][0] + red[0][1] + red[0][2] + red[0][3];
  sq  = red[1][0] + red[1][1] + red[1][2] + red[1][3];
  const float mean = sum * (1.f / D);
  const float var = sq * (1.f / D) - mean * mean;
  const float rs = rsqrtf(var + 1e-5f);
  const float4 gv = *(const float4*)&g[tid * 4];
  const float4 bv = *(const float4*)&bta[tid * 4];
  const float o0 = (s0 - mean) * rs * gv.x + bv.x;
  const float o1 = (s1 - mean) * rs * gv.y + bv.y;
  const float o2 = (s2 - mean) * rs * gv.z + bv.z;
  const float o3 = (s3 - mean) * rs * gv.w + bv.w;
  *(float4*)&h[off] = make_float4(o0, o1, o2, o3);
  const unsigned int lo = (unsigned)f2bf(o0) | ((unsigned)f2bf(o1) << 16);
  const unsigned int hi = (unsigned)f2bf(o2) | ((unsigned)f2bf(o3) << 16);
  *(uint2*)&hb[off] = make_uint2(lo, hi);
}

// ---------------- MFMA attention: one block (4 waves) per (batch, head) ----------------
__global__ __launch_bounds__(256) void attn_kernel(const u16* __restrict__ qkv,
    const float* __restrict__ rel, u16* __restrict__ ctxb){
  __shared__ u16 Qf[8 * 81 * 8];
  __shared__ u16 Kf[8 * 81 * 8];
  __shared__ u16 Vf[12 * 65 * 8];
  __shared__ u16 Pf[12 * 81 * 8];
  __shared__ float Ss[TP][84];
  const int bh = blockIdx.x;
  const int b = bh >> 4, hh = bh & 15;
  const int tid = threadIdx.x, w = tid >> 6, l = tid & 63;
  const size_t qvbase = (size_t)(b * TT) * QS + hh * DKH;
  const size_t obase  = (size_t)(b * TT) * D + hh * DKH;

  {
    const int r0 = tid >> 4, c4 = (tid & 15) * 4;
    const int g = c4 >> 3, e = c4 & 7;
    for (int r = r0; r < TP; r += 16){
      uint2 q2 = make_uint2(0u, 0u), k2 = make_uint2(0u, 0u);
      if (r < TT){
        q2 = *(const uint2*)&qkv[qvbase + (size_t)r * QS + c4];
        k2 = *(const uint2*)&qkv[qvbase + 1024 + (size_t)r * QS + c4];
      }
      *(uint2*)&Qf[(g * 81 + r) * 8 + e] = q2;
      *(uint2*)&Kf[(g * 81 + r) * 8 + e] = k2;
    }
    for (int j = r0; j < KP; j += 16){
      u16 v4[4] = {0, 0, 0, 0};
      if (j < TT) *(uint2*)v4 = *(const uint2*)&qkv[qvbase + 2048 + (size_t)j * QS + c4];
      const int gg = j >> 3, ee = j & 7;
      #pragma unroll
      for (int d = 0; d < 4; d++)
        Vf[(gg * 65 + (c4 + d)) * 8 + ee] = v4[d];
    }
  }
  __syncthreads();

  const int fr = l & 15, gg = l >> 4;
  for (int p = w; p < 25; p += 4){
    const int rt = p / 5, ct = p % 5;
    f32x4 acc = {};
    #pragma unroll
    for (int kk = 0; kk < 2; kk++){
      const short8 a  = *(const short8*)&Qf[((kk * 4 + gg) * 81 + rt * 16 + fr) * 8];
      const short8 bf = *(const short8*)&Kf[((kk * 4 + gg) * 81 + ct * 16 + fr) * 8];
      acc = __builtin_amdgcn_mfma_f32_16x16x32_bf16(a, bf, acc, 0, 0, 0);
    }
    const int col = ct * 16 + fr;
    #pragma unroll
    for (int r = 0; r < 4; r++){
      const int row = rt * 16 + gg * 4 + r;
      float sv = -1e30f;
      if (row < TT && col < TT)
        sv = acc[r] * 0.125f + rel[((size_t)hh * 78 + row) * 78 + col];
      Ss[row][col] = sv;
    }
  }
  __syncthreads();

  for (int row = w; row < TP; row += 4){
    const float s1 = Ss[row][l];
    const float s2 = (l < 16) ? Ss[row][64 + l] : -1e30f;
    float mx = fmaxf(s1, s2);
    #pragma unroll
    for (int m = 32; m >= 1; m >>= 1) mx = fmaxf(mx, __shfl_xor(mx, m));
    const float e1 = __expf(s1 - mx);
    const float e2 = (l < 16) ? __expf(s2 - mx) : 0.f;
    float sum = e1 + e2;
    #pragma unroll
    for (int m = 32; m >= 1; m >>= 1) sum += __shfl_xor(sum, m);
    const float inv = 1.f / sum;
    Pf[((l >> 3) * 81 + row) * 8 + (l & 7)] = f2bf(e1 * inv);
    if (l < 16){
      Pf[((8  + (l >> 3)) * 81 + row) * 8 + (l & 7)] = f2bf(e2 * inv);
      Pf[((10 + (l >> 3)) * 81 + row) * 8 + (l & 7)] = 0;
    }
  }
  __syncthreads();

  for (int p = w; p < 20; p += 4){
    const int rt = p >> 2, ct = p & 3;
    f32x4 acc = {};
    #pragma unroll
    for (int kk = 0; kk < 3; kk++){
      const short8 a  = *(const short8*)&Pf[((kk * 4 + gg) * 81 + rt * 16 + fr) * 8];
      const short8 bf = *(const short8*)&Vf[((kk * 4 + gg) * 65 + ct * 16 + fr) * 8];
      acc = __builtin_amdgcn_mfma_f32_16x16x32_bf16(a, bf, acc, 0, 0, 0);
    }
    #pragma unroll
    for (int r = 0; r < 4; r++){
      const int row = rt * 16 + gg * 4 + r;
      if (row < TT)
        ctxb[obase + (size_t)row * D + ct * 16 + fr] = f2bf(acc[r]);
    }
  }
}

// ---------------- 128x128 bf16 MFMA GEMM: dbuf + stage-ahead (min 2-phase pipeline),
// XCD-chunked N-fast grid swizzle.  One __syncthreads per K-step; STAGE(k+1) issued
// before ds_read/MFMA of tile k so HBM latency hides under compute.
template<int OBF16, int BIAS, int GELU>
__global__ __launch_bounds__(256, 2) void gemm_bt(
    const u16* __restrict__ A, int lda,
    const u16* __restrict__ Bt,
    void* __restrict__ Cv, int ldc,
    const float* __restrict__ bias, int K, int nby)
{
  __shared__ u16 As[2][128 * 32];
  __shared__ u16 Bs[2][128 * 32];
  // bijective XCD-chunked swizzle (m204) + N-fast decode
  const int nwg = gridDim.x, bid = blockIdx.x;
  const int q8 = nwg >> 3, r8 = nwg & 7;
  const int xcd = bid & 7, off = bid >> 3;
  const int wg = (xcd < r8 ? xcd * (q8 + 1) : r8 * (q8 + 1) + (xcd - r8) * q8) + off;
  const int m0 = (wg / nby) * 128, n0 = (wg % nby) * 128;

  const int tid = threadIdx.x;
  const int l = tid & 63, w = tid >> 6;
  const int wr = w >> 1, wc = w & 1;
  f32x4 acc[4][4] = {};
  const int lr = l >> 2;
  const int lseg = (l & 3) * 8;
  const u16* ga0 = A + (size_t)(m0 + w * 32 + lr) * lda + lseg;
  const u16* ga1 = A + (size_t)(m0 + w * 32 + 16 + lr) * lda + lseg;
  const u16* gb0 = Bt + (size_t)(n0 + w * 32 + lr) * K + lseg;
  const u16* gb1 = Bt + (size_t)(n0 + w * 32 + 16 + lr) * K + lseg;
  const int fr = l & 15, kg = (l >> 4) * 8;

#define STAGE(sel, kc) do { \
    gload16(ga0 + (kc), &As[sel][(w * 32) * 32]); \
    gload16(ga1 + (kc), &As[sel][(w * 32 + 16) * 32]); \
    gload16(gb0 + (kc), &Bs[sel][(w * 32) * 32]); \
    gload16(gb1 + (kc), &Bs[sel][(w * 32 + 16) * 32]); \
  } while (0)

  const int nkt = K >> 5;
  STAGE(0, 0);
  __syncthreads();
  int cur = 0;
  #pragma unroll 1
  for (int kt = 0; kt < nkt; ++kt){
    if (kt + 1 < nkt) STAGE(cur ^ 1, (kt + 1) * 32);
    short8 af[4], bf[4];
    #pragma unroll
    for (int i = 0; i < 4; i++){
      af[i] = *(const short8*)&As[cur][(wr * 64 + i * 16 + fr) * 32 + kg];
      bf[i] = *(const short8*)&Bs[cur][(wc * 64 + i * 16 + fr) * 32 + kg];
    }
    #pragma unroll
    for (int i = 0; i < 4; i++)
      #pragma unroll
      for (int j = 0; j < 4; j++)
        acc[i][j] = __builtin_amdgcn_mfma_f32_16x16x32_bf16(af[i], bf[j], acc[i][j], 0, 0, 0);
    __syncthreads();   // drains vmcnt (next tile landed) + lgkm; releases buf for overwrite
    cur ^= 1;
  }
#undef STAGE

  const int rg = (l >> 4) * 4;
  #pragma unroll
  for (int i = 0; i < 4; i++){
    #pragma unroll
    for (int j = 0; j < 4; j++){
      const int col = n0 + wc * 64 + j * 16 + fr;
      const float bv = BIAS ? bias[col] : 0.f;
      #pragma unroll
      for (int r = 0; r < 4; r++){
        const int row = m0 + wr * 64 + i * 16 + rg + r;
        float xv = acc[i][j][r] + bv;
        if (GELU) xv = 0.5f * xv * (1.f + erff(xv * 0.70710678118f));
        if (OBF16) ((u16*)Cv)[(size_t)row * ldc + col] = f2bf(xv);
        else       ((float*)Cv)[(size_t)row * ldc + col] = xv;
      }
    }
  }
}

extern "C" void kernel_launch(void* const* d_in, const int* in_sizes, int n_in,
                              void* d_out, int out_size, void* d_ws, size_t ws_size,
                              hipStream_t stream) {
  const int*   x       = (const int*)  d_in[0];
  const float* emb     = (const float*)d_in[1];
  const float* pool    = (const float*)d_in[2];
  const float* Wq      = (const float*)d_in[3];
  const float* Wk      = (const float*)d_in[4];
  const float* Wv      = (const float*)d_in[5];
  const float* Wo      = (const float*)d_in[6];
  const float* rel     = (const float*)d_in[7];
  const float* ln1_g   = (const float*)d_in[8];
  const float* ln1_b   = (const float*)d_in[9];
  const float* ln2_g   = (const float*)d_in[10];
  const float* ln2_b   = (const float*)d_in[11];
  const float* W1      = (const float*)d_in[12];
  const float* b1      = (const float*)d_in[13];
  const float* W2      = (const float*)d_in[14];
  const float* b2      = (const float*)d_in[15];
  const float* Wout    = (const float*)d_in[16];
  const float* bout    = (const float*)d_in[17];
  float* out = (float*)d_out;

  const size_t SZ_WDD  = (size_t)D * D * 2;
  const size_t SZ_WDF  = (size_t)D * DFF * 2;
  const size_t SZ_H    = (size_t)ROWS * D * 4;
  const size_t SZ_HB   = (size_t)ROWS * D * 2;
  const size_t need = 4*SZ_WDD + 3*SZ_WDF + SZ_H + 6*SZ_HB;
  if (ws_size < need) return;

  char* p = (char*)d_ws;
  u16* WqkvT = (u16*)p; p += 3*SZ_WDD;   // rows [0,1024)=Wq^T, [1024,2048)=Wk^T, [2048,3072)=Wv^T
  u16* WoT   = (u16*)p; p += SZ_WDD;
  u16* W1T   = (u16*)p; p += SZ_WDF;
  u16* W2T   = (u16*)p; p += SZ_WDF;
  u16* WouT  = (u16*)p; p += SZ_WDF;
  float* h   = (float*)p; p += SZ_H;
  u16* hb    = (u16*)p; p += SZ_HB;
  u16* qkv   = (u16*)p; p += 3*SZ_HB;    // [ROWS][3072]
  u16* ctxb  = (u16*)p; p += SZ_HB;
  u16* gb    = qkv;                       // FFN hidden aliases qkv+ctx
  u16* tmpb  = (u16*)p; p += SZ_HB;       // residual-branch, bf16 now

  dim3 tb(32, 8);
  transpose_cast<<<dim3(VOCAB/32, D/32), tb, 0, stream>>>(Wout, WouT, D, VOCAB);
  embed_kernel<<<ROWS, 256, 0, stream>>>(x, emb, pool, h, hb);

  const int MB = ROWS / 128;   // 134
  for (int l = 0; l < LAYERS; ++l){
    const size_t wo = (size_t)l * D * D;
    const size_t wf = (size_t)l * D * DFF;
    transpose6<<<12288, tb, 0, stream>>>(Wq + wo, Wk + wo, Wv + wo, Wo + wo,
                                         W1 + wf, W2 + wf, WqkvT, WoT, W1T, W2T);

    gemm_bt<1,0,0><<<MB * (QS/128),  256, 0, stream>>>(hb, D, WqkvT, qkv, QS, nullptr, D, QS/128);
    attn_kernel<<<BATCH*NH, 256, 0, stream>>>(qkv, rel + (size_t)l*NH*78*78, ctxb);
    gemm_bt<1,0,0><<<MB * (D/128),   256, 0, stream>>>(ctxb, D, WoT, tmpb, D, nullptr, D, D/128);
    ln_kernel<<<ROWS, 256, 0, stream>>>(h, tmpb, hb, ln1_g + l*D, ln1_b + l*D);
    gemm_bt<1,1,1><<<MB * (DFF/128), 256, 0, stream>>>(hb, D, W1T, gb, DFF, b1 + l*DFF, D, DFF/128);
    gemm_bt<1,1,0><<<MB * (D/128),   256, 0, stream>>>(gb, DFF, W2T, tmpb, D, b2 + l*D, DFF, D/128);
    ln_kernel<<<ROWS, 256, 0, stream>>>(h, tmpb, hb, ln2_g + l*D, ln2_b + l*D);
  }
  gemm_bt<0,1,0><<<(BATCH/128) * (VOCAB/128), 256, 0, stream>>>(
      hb, TT * D, WouT, out, VOCAB, bout, D, VOCAB/128);
}